// Round 1
// baseline (2332.227 us; speedup 1.0000x reference)
//
#include <hip/hip_runtime.h>
#include <math.h>

#define S_   2048
#define D_   1024
#define H_   16
#define DFF_ 4096

#define NEGINF (-__builtin_huge_valf())

// ---------------- LayerNorm: one row (1024 floats) per 256-thread block ----------------
__global__ __launch_bounds__(256) void ln_kernel(
    const float* __restrict__ x, const float* __restrict__ w,
    const float* __restrict__ b, float* __restrict__ y)
{
    const int row = blockIdx.x;
    const int t = threadIdx.x;
    const float4 v = reinterpret_cast<const float4*>(x + (size_t)row * D_)[t];
    float s  = v.x + v.y + v.z + v.w;
    float ss = v.x*v.x + v.y*v.y + v.z*v.z + v.w*v.w;
    #pragma unroll
    for (int o = 32; o; o >>= 1) {
        s  += __shfl_xor(s,  o, 64);
        ss += __shfl_xor(ss, o, 64);
    }
    __shared__ float red[8];
    const int wid = t >> 6, lane = t & 63;
    if (lane == 0) { red[wid] = s; red[4 + wid] = ss; }
    __syncthreads();
    s  = red[0] + red[1] + red[2] + red[3];
    ss = red[4] + red[5] + red[6] + red[7];
    const float mean = s * (1.f / D_);
    const float var  = ss * (1.f / D_) - mean * mean;
    const float rstd = rsqrtf(var + 1e-5f);
    const float4 wv = reinterpret_cast<const float4*>(w)[t];
    const float4 bv = reinterpret_cast<const float4*>(b)[t];
    float4 o;
    o.x = (v.x - mean) * rstd * wv.x + bv.x;
    o.y = (v.y - mean) * rstd * wv.y + bv.y;
    o.z = (v.z - mean) * rstd * wv.z + bv.z;
    o.w = (v.w - mean) * rstd * wv.w + bv.w;
    reinterpret_cast<float4*>(y + (size_t)row * D_)[t] = o;
}

// ---------------- SGEMM: C[M,N] = A[M,K] @ B[K,N] (+bias, +relu / +residual) ----------
// 128x128 tile, BK=16, 256 threads, 8x8 per thread in 4x 4x4 quadrants
// (row/col split at +64 keeps LDS reads at worst 2-way conflicted = free).
template<int EPI>  // 0: +bias   1: +bias,relu   2: +bias,+residual
__global__ __launch_bounds__(256) void sgemm_kernel(
    const float* __restrict__ A, const float* __restrict__ Bm,
    const float* __restrict__ bias, const float* __restrict__ res,
    float* __restrict__ C, int M, int N, int K)
{
    __shared__ __align__(16) float As[16][132];   // stored transposed: As[k][m]
    __shared__ __align__(16) float Bs[16][132];   // Bs[k][n]
    const int tid = threadIdx.x;
    const int tx = tid & 15, ty = tid >> 4;
    const int row0 = blockIdx.y * 128, col0 = blockIdx.x * 128;

    float acc[8][8];
    #pragma unroll
    for (int i = 0; i < 8; ++i)
        #pragma unroll
        for (int j = 0; j < 8; ++j) acc[i][j] = 0.f;

    const int la_r = tid >> 2;          // 0..63  (A tile row, +64 for second half)
    const int la_c = (tid & 3) << 2;    // 0,4,8,12 (k within tile)
    const int lb_k = tid >> 5;          // 0..7   (B tile k, +8 for second half)
    const int lb_n = (tid & 31) << 2;   // 0..124

    for (int kt = 0; kt < K; kt += 16) {
        const float4 a0 = *(const float4*)(A + (size_t)(row0 + la_r)      * K + kt + la_c);
        const float4 a1 = *(const float4*)(A + (size_t)(row0 + la_r + 64) * K + kt + la_c);
        const float4 b0 = *(const float4*)(Bm + (size_t)(kt + lb_k)     * N + col0 + lb_n);
        const float4 b1 = *(const float4*)(Bm + (size_t)(kt + lb_k + 8) * N + col0 + lb_n);
        __syncthreads();   // previous iteration's LDS reads complete
        As[la_c+0][la_r] = a0.x; As[la_c+1][la_r] = a0.y;
        As[la_c+2][la_r] = a0.z; As[la_c+3][la_r] = a0.w;
        As[la_c+0][la_r+64] = a1.x; As[la_c+1][la_r+64] = a1.y;
        As[la_c+2][la_r+64] = a1.z; As[la_c+3][la_r+64] = a1.w;
        *(float4*)&Bs[lb_k][lb_n]     = b0;
        *(float4*)&Bs[lb_k + 8][lb_n] = b1;
        __syncthreads();
        #pragma unroll
        for (int k = 0; k < 16; ++k) {
            float a_[8], b_[8];
            *(float4*)&a_[0] = *(const float4*)&As[k][ty * 4];
            *(float4*)&a_[4] = *(const float4*)&As[k][64 + ty * 4];
            *(float4*)&b_[0] = *(const float4*)&Bs[k][tx * 4];
            *(float4*)&b_[4] = *(const float4*)&Bs[k][64 + tx * 4];
            #pragma unroll
            for (int i = 0; i < 8; ++i)
                #pragma unroll
                for (int j = 0; j < 8; ++j)
                    acc[i][j] = fmaf(a_[i], b_[j], acc[i][j]);
        }
    }

    #pragma unroll
    for (int qr = 0; qr < 2; ++qr)
    #pragma unroll
    for (int i = 0; i < 4; ++i) {
        const int row = row0 + qr * 64 + ty * 4 + i;
        #pragma unroll
        for (int qc = 0; qc < 2; ++qc) {
            const int col = col0 + qc * 64 + tx * 4;
            const float4 bv = *(const float4*)(bias + col);
            float4 r;
            r.x = acc[qr*4+i][qc*4+0] + bv.x;
            r.y = acc[qr*4+i][qc*4+1] + bv.y;
            r.z = acc[qr*4+i][qc*4+2] + bv.z;
            r.w = acc[qr*4+i][qc*4+3] + bv.w;
            if (EPI == 1) {
                r.x = fmaxf(r.x, 0.f); r.y = fmaxf(r.y, 0.f);
                r.z = fmaxf(r.z, 0.f); r.w = fmaxf(r.w, 0.f);
            }
            if (EPI == 2) {
                const float4 rv = *(const float4*)(res + (size_t)row * N + col);
                r.x += rv.x; r.y += rv.y; r.z += rv.z; r.w += rv.w;
            }
            *(float4*)(C + (size_t)row * N + col) = r;
        }
    }
}

// ---------------- Flash attention with ALiBi, causal -----------------------------------
// Grid: B*H*(S/64). Block: 256 = 4 waves; wave owns 16 q-rows; lane owns head-dim d=lane.
// qT transposed in LDS (stride 68 -> aligned float4 broadcasts); K/V padded 65 (conflict-
// free per-lane column reads); P staged per wave (stride 20 -> aligned b128 broadcasts).
__global__ __launch_bounds__(256) void attn_kernel(
    const float* __restrict__ qkv, float* __restrict__ ctx)
{
    const int qt  = blockIdx.x & 31;        // q tile (S/64 = 32)
    const int bh  = blockIdx.x >> 5;
    const int b   = bh >> 4, h = bh & 15;
    const int tid = threadIdx.x;
    const int wid = tid >> 6, lane = tid & 63;
    const int i0  = qt << 6;
    const int r0  = wid << 4;               // wave's local row base
    const float slope = exp2f(-(float)h);

    __shared__ __align__(16) float qT[64 * 68];      // [d][local_row]
    __shared__ __align__(16) float Ks[64 * 65];      // [key][d]
    __shared__ __align__(16) float Vs[64 * 65];      // [key][d]
    __shared__ __align__(16) float Ps[4 * 64 * 20];  // [wave][key][row]

    const size_t row_base = (size_t)b * S_;

    #pragma unroll
    for (int r = 0; r < 4; ++r) {           // load Q tile, transposed
        const int idx4 = tid + (r << 8);
        const int jj = idx4 >> 4;
        const int dd = (idx4 & 15) << 2;
        const float4 v = *(const float4*)(qkv + (row_base + i0 + jj) * 3072 + h * 64 + dd);
        qT[(dd+0)*68 + jj] = v.x;
        qT[(dd+1)*68 + jj] = v.y;
        qT[(dd+2)*68 + jj] = v.z;
        qT[(dd+3)*68 + jj] = v.w;
    }

    float m[16], l[16], acc[16];
    #pragma unroll
    for (int r = 0; r < 16; ++r) { m[r] = NEGINF; l[r] = 0.f; acc[r] = 0.f; }

    for (int kt = 0; kt <= qt; ++kt) {
        const int j0 = kt << 6;
        float4 kf[4], vf[4];                // prefetch before barrier
        #pragma unroll
        for (int r = 0; r < 4; ++r) {
            const int idx4 = tid + (r << 8);
            const int jj = idx4 >> 4;
            const int dd = (idx4 & 15) << 2;
            const size_t rp = (row_base + j0 + jj) * 3072 + h * 64 + dd;
            kf[r] = *(const float4*)(qkv + rp + 1024);
            vf[r] = *(const float4*)(qkv + rp + 2048);
        }
        __syncthreads();                    // prev tile's LDS reads done
        #pragma unroll
        for (int r = 0; r < 4; ++r) {
            const int idx4 = tid + (r << 8);
            const int jj = idx4 >> 4;
            const int dd = (idx4 & 15) << 2;
            Ks[jj*65 + dd+0] = kf[r].x; Ks[jj*65 + dd+1] = kf[r].y;
            Ks[jj*65 + dd+2] = kf[r].z; Ks[jj*65 + dd+3] = kf[r].w;
            Vs[jj*65 + dd+0] = vf[r].x; Vs[jj*65 + dd+1] = vf[r].y;
            Vs[jj*65 + dd+2] = vf[r].z; Vs[jj*65 + dd+3] = vf[r].w;
        }
        __syncthreads();                    // also orders qT writes on first iter

        // ---- QK^T: this lane's key column j = j0+lane, 16 rows
        float s[16];
        #pragma unroll
        for (int r = 0; r < 16; ++r) s[r] = 0.f;
        const float* kp = &Ks[lane * 65];
        #pragma unroll 2
        for (int d = 0; d < 64; ++d) {
            const float kd = kp[d];
            const float* qd = &qT[d * 68 + r0];
            #pragma unroll
            for (int r4 = 0; r4 < 4; ++r4) {
                const float4 q4 = *(const float4*)(qd + (r4 << 2));
                s[r4*4+0] = fmaf(q4.x, kd, s[r4*4+0]);
                s[r4*4+1] = fmaf(q4.y, kd, s[r4*4+1]);
                s[r4*4+2] = fmaf(q4.z, kd, s[r4*4+2]);
                s[r4*4+3] = fmaf(q4.w, kd, s[r4*4+3]);
            }
        }

        // ---- bias + causal mask + online softmax (per row; reductions across 64 lanes)
        const int j = j0 + lane;
        float p[16];
        #pragma unroll
        for (int r = 0; r < 16; ++r) {
            const int i = i0 + r0 + r;
            float sv = (j <= i) ? fmaf(slope, (float)(j - i), s[r] * 0.125f) : NEGINF;
            float mx = sv;
            #pragma unroll
            for (int o = 32; o; o >>= 1) mx = fmaxf(mx, __shfl_xor(mx, o, 64));
            const float mnew = fmaxf(m[r], mx);
            const float corr = __expf(m[r] - mnew);  // m=-inf, mnew finite -> 0 (no NaN)
            const float pv   = __expf(sv - mnew);    // masked -> exp(-inf)=0
            float ps = pv;
            #pragma unroll
            for (int o = 32; o; o >>= 1) ps += __shfl_xor(ps, o, 64);
            l[r]   = l[r] * corr + ps;
            acc[r] *= corr;
            m[r]   = mnew;
            p[r]   = pv;
        }

        // ---- stage P for this wave: Ps[wid][key=lane][row]
        float* pw = &Ps[(wid * 64 + lane) * 20];
        #pragma unroll
        for (int r4 = 0; r4 < 4; ++r4)
            *(float4*)(pw + (r4 << 2)) =
                make_float4(p[r4*4+0], p[r4*4+1], p[r4*4+2], p[r4*4+3]);
        asm volatile("" ::: "memory");      // wave-internal LDS RAW: block reordering

        // ---- PV: acc[r] += sum_j P[r][j] * V[j][lane]
        const float* vp = &Vs[lane];
        const float* pbase = &Ps[wid * 64 * 20];
        #pragma unroll 2
        for (int jj = 0; jj < 64; ++jj) {
            const float vv = vp[jj * 65];
            const float* pj = pbase + jj * 20;
            #pragma unroll
            for (int r4 = 0; r4 < 4; ++r4) {
                const float4 p4 = *(const float4*)(pj + (r4 << 2));
                acc[r4*4+0] = fmaf(p4.x, vv, acc[r4*4+0]);
                acc[r4*4+1] = fmaf(p4.y, vv, acc[r4*4+1]);
                acc[r4*4+2] = fmaf(p4.z, vv, acc[r4*4+2]);
                acc[r4*4+3] = fmaf(p4.w, vv, acc[r4*4+3]);
            }
        }
    }

    // ---- write ctx in [b, s, h*64+d] layout (out-proj becomes a plain GEMM)
    #pragma unroll
    for (int r = 0; r < 16; ++r) {
        const int i = i0 + r0 + r;
        ctx[(row_base + i) * D_ + h * 64 + lane] = acc[r] / l[r];
    }
}

// ---------------- launch ----------------------------------------------------------------
extern "C" void kernel_launch(void* const* d_in, const int* in_sizes, int n_in,
                              void* d_out, int out_size, void* d_ws, size_t ws_size,
                              hipStream_t stream) {
    const float* src     = (const float*)d_in[0];
    const float* norm_w  = (const float*)d_in[1];
    const float* norm_b  = (const float*)d_in[2];
    const float* wqkv_w  = (const float*)d_in[3];
    const float* wqkv_b  = (const float*)d_in[4];
    const float* out_w   = (const float*)d_in[5];
    const float* out_b   = (const float*)d_in[6];
    const float* fnorm_w = (const float*)d_in[7];
    const float* fnorm_b = (const float*)d_in[8];
    const float* ff1_w   = (const float*)d_in[9];
    const float* ff1_b   = (const float*)d_in[10];
    const float* ff2_w   = (const float*)d_in[11];
    const float* ff2_b   = (const float*)d_in[12];
    float* out = (float*)d_out;

    const int M = 2 * S_;                       // 4096 rows
    float* ws    = (float*)d_ws;                // all offsets in floats
    float* h1    = ws;                          // [0, 4M)    16 MB
    float* qkvb  = ws + (size_t)4  * 1024 * 1024;  // [4M, 16M)  48 MB
    float* ctx   = ws;                          // reuse h1 (dead after QKV GEMM)
    float* ffmid = ws + (size_t)4  * 1024 * 1024;  // [4M, 20M)  reuse qkv (dead after attn)
    float* src2  = ws + (size_t)20 * 1024 * 1024;  // [20M, 24M)
    float* h2    = ws + (size_t)24 * 1024 * 1024;  // [24M, 28M)  -> 112 MB total

    // 1) h1 = LN(src)
    ln_kernel<<<M, 256, 0, stream>>>(src, norm_w, norm_b, h1);
    // 2) qkv = h1 @ wqkv_w + wqkv_b       [4096 x 3072]
    sgemm_kernel<0><<<dim3(3072/128, M/128), 256, 0, stream>>>(
        h1, wqkv_w, wqkv_b, nullptr, qkvb, M, 3072, D_);
    // 3) ctx = flash-attn(q,k,v)          [4096 x 1024]
    attn_kernel<<<2 * H_ * (S_ / 64), 256, 0, stream>>>(qkvb, ctx);
    // 4) src2 = src + ctx @ out_w + out_b
    sgemm_kernel<2><<<dim3(D_/128, M/128), 256, 0, stream>>>(
        ctx, out_w, out_b, src, src2, M, D_, D_);
    // 5) h2 = LN(src2)
    ln_kernel<<<M, 256, 0, stream>>>(src2, fnorm_w, fnorm_b, h2);
    // 6) ffmid = relu(h2 @ ff1_w + ff1_b) [4096 x 4096]
    sgemm_kernel<1><<<dim3(DFF_/128, M/128), 256, 0, stream>>>(
        h2, ff1_w, ff1_b, nullptr, ffmid, M, DFF_, D_);
    // 7) out = src2 + ffmid @ ff2_w + ff2_b
    sgemm_kernel<2><<<dim3(D_/128, M/128), 256, 0, stream>>>(
        ffmid, ff2_w, ff2_b, src2, out, M, D_, DFF_);
}

// Round 2
// 1209.538 us; speedup vs baseline: 1.9282x; 1.9282x over previous
//
#include <hip/hip_runtime.h>
#include <math.h>

#define S_   2048
#define D_   1024
#define H_   16
#define DFF_ 4096

#define NEGINF (-__builtin_huge_valf())

typedef __bf16 bf16x8 __attribute__((ext_vector_type(8)));
typedef float  f32x4  __attribute__((ext_vector_type(4)));

static __device__ __forceinline__ unsigned short f2bf_rne(float f) {
    unsigned int u = __float_as_uint(f);
    u = (u + 0x7fffu + ((u >> 16) & 1u)) >> 16;
    return (unsigned short)u;
}

// ---------------- LayerNorm: one row (1024 floats) per 256-thread block ----------------
template<bool OBF>
__global__ __launch_bounds__(256) void ln_kernel(
    const float* __restrict__ x, const float* __restrict__ w,
    const float* __restrict__ b, void* __restrict__ y)
{
    const int row = blockIdx.x;
    const int t = threadIdx.x;
    const float4 v = reinterpret_cast<const float4*>(x + (size_t)row * D_)[t];
    float s  = v.x + v.y + v.z + v.w;
    float ss = v.x*v.x + v.y*v.y + v.z*v.z + v.w*v.w;
    #pragma unroll
    for (int o = 32; o; o >>= 1) {
        s  += __shfl_xor(s,  o, 64);
        ss += __shfl_xor(ss, o, 64);
    }
    __shared__ float red[8];
    const int wid = t >> 6, lane = t & 63;
    if (lane == 0) { red[wid] = s; red[4 + wid] = ss; }
    __syncthreads();
    s  = red[0] + red[1] + red[2] + red[3];
    ss = red[4] + red[5] + red[6] + red[7];
    const float mean = s * (1.f / D_);
    const float var  = ss * (1.f / D_) - mean * mean;
    const float rstd = rsqrtf(var + 1e-5f);
    const float4 wv = reinterpret_cast<const float4*>(w)[t];
    const float4 bv = reinterpret_cast<const float4*>(b)[t];
    float4 o;
    o.x = (v.x - mean) * rstd * wv.x + bv.x;
    o.y = (v.y - mean) * rstd * wv.y + bv.y;
    o.z = (v.z - mean) * rstd * wv.z + bv.z;
    o.w = (v.w - mean) * rstd * wv.w + bv.w;
    if (OBF) {
        ushort4 o4;
        o4.x = f2bf_rne(o.x); o4.y = f2bf_rne(o.y);
        o4.z = f2bf_rne(o.z); o4.w = f2bf_rne(o.w);
        reinterpret_cast<ushort4*>((unsigned short*)y + (size_t)row * D_)[t] = o4;
    } else {
        reinterpret_cast<float4*>((float*)y + (size_t)row * D_)[t] = o;
    }
}

// ---------------- Weight transpose + cast: fp32 [K][N] -> bf16 [N][K] ------------------
__global__ __launch_bounds__(256) void wcast_kernel(
    const float* __restrict__ in, unsigned short* __restrict__ outT, int K, int N)
{
    __shared__ float t[64][65];
    const int n0 = blockIdx.x * 64, k0 = blockIdx.y * 64;
    const int tid = threadIdx.x;
    #pragma unroll
    for (int i = 0; i < 16; ++i) {
        const int idx = i * 256 + tid;
        const int kk = idx >> 6, nn = idx & 63;
        t[kk][nn] = in[(size_t)(k0 + kk) * N + n0 + nn];
    }
    __syncthreads();
    #pragma unroll
    for (int i = 0; i < 16; ++i) {
        const int idx = i * 256 + tid;
        const int nn = idx >> 6, kk = idx & 63;
        outT[(size_t)(n0 + nn) * K + k0 + kk] = f2bf_rne(t[kk][nn]);
    }
}

// ---------------- bf16 MFMA GEMM: C[M,N] = A[M,K] @ Bt[N,K]^T (+bias, epi) -------------
// m97 structure: 128x128 tile, BK=32, 256 threads = 4 waves, each wave a 64x64 quadrant
// of 4x4 16x16x32 MFMA fragments; global_load_lds width-16 staging, 2 barriers/K-step.
template<int EPI, bool OBF>  // EPI 0: +bias  1: +bias,relu  2: +bias,+residual
__global__ __launch_bounds__(256) void bgemm_kernel(
    const __bf16* __restrict__ A,   // [M][K] bf16
    const __bf16* __restrict__ Bt,  // [N][K] bf16 (pre-transposed)
    const float* __restrict__ bias, const float* __restrict__ res,
    void* __restrict__ Cv, int M, int N, int K)
{
    __shared__ __align__(16) __bf16 As[128 * 32];
    __shared__ __align__(16) __bf16 Bs[128 * 32];
    const int tid  = threadIdx.x;
    const int w    = tid >> 6, lane = tid & 63;
    const int wr   = w >> 1, wc = w & 1;
    const int row0 = blockIdx.y * 128, col0 = blockIdx.x * 128;

    const int lrow = lane >> 2;          // staging: row within 16-row chunk
    const int lchk = (lane & 3) * 8;     // staging: k-offset (8 bf16 = 16B)
    const int frow = lane & 15;          // fragment row/col
    const int fk   = (lane >> 4) * 8;    // fragment k-offset

    f32x4 acc[4][4] = {};

    for (int kt = 0; kt < K; kt += 32) {
        #pragma unroll
        for (int it = 0; it < 2; ++it) {
            const int arow = w * 32 + it * 16;   // wave-uniform
            __builtin_amdgcn_global_load_lds(
                (__attribute__((address_space(1))) void*)(A + (size_t)(row0 + arow + lrow) * K + kt + lchk),
                (__attribute__((address_space(3))) void*)(&As[arow * 32]), 16, 0, 0);
            __builtin_amdgcn_global_load_lds(
                (__attribute__((address_space(1))) void*)(Bt + (size_t)(col0 + arow + lrow) * K + kt + lchk),
                (__attribute__((address_space(3))) void*)(&Bs[arow * 32]), 16, 0, 0);
        }
        __syncthreads();   // drains vmcnt: LDS staged; prev iter's reads done before issue
        bf16x8 af[4], bfr[4];
        #pragma unroll
        for (int i = 0; i < 4; ++i) {
            af[i]  = *(const bf16x8*)&As[(wr * 64 + i * 16 + frow) * 32 + fk];
            bfr[i] = *(const bf16x8*)&Bs[(wc * 64 + i * 16 + frow) * 32 + fk];
        }
        #pragma unroll
        for (int mi = 0; mi < 4; ++mi)
            #pragma unroll
            for (int ni = 0; ni < 4; ++ni)
                acc[mi][ni] = __builtin_amdgcn_mfma_f32_16x16x32_bf16(
                    af[mi], bfr[ni], acc[mi][ni], 0, 0, 0);
        __syncthreads();
    }

    // epilogue: C/D layout col = lane&15, row = (lane>>4)*4 + reg   [m89/m91 verified]
    float bz[4];
    #pragma unroll
    for (int ni = 0; ni < 4; ++ni) bz[ni] = bias[col0 + wc * 64 + ni * 16 + frow];
    #pragma unroll
    for (int mi = 0; mi < 4; ++mi) {
        #pragma unroll
        for (int j = 0; j < 4; ++j) {
            const int row = row0 + wr * 64 + mi * 16 + (lane >> 4) * 4 + j;
            #pragma unroll
            for (int ni = 0; ni < 4; ++ni) {
                const int col = col0 + wc * 64 + ni * 16 + frow;
                float v = acc[mi][ni][j] + bz[ni];
                if (EPI == 1) v = fmaxf(v, 0.f);
                if (EPI == 2) v += res[(size_t)row * N + col];
                if (OBF) ((unsigned short*)Cv)[(size_t)row * N + col] = f2bf_rne(v);
                else     ((float*)Cv)[(size_t)row * N + col] = v;
            }
        }
    }
}

// ---------------- Flash attention with ALiBi, causal (fp32; ctx out bf16) --------------
__global__ __launch_bounds__(256) void attn_kernel(
    const float* __restrict__ qkv, unsigned short* __restrict__ ctx)
{
    const int qt  = blockIdx.x & 31;
    const int bh  = blockIdx.x >> 5;
    const int b   = bh >> 4, h = bh & 15;
    const int tid = threadIdx.x;
    const int wid = tid >> 6, lane = tid & 63;
    const int i0  = qt << 6;
    const int r0  = wid << 4;
    const float slope = exp2f(-(float)h);

    __shared__ __align__(16) float qT[64 * 68];
    __shared__ __align__(16) float Ks[64 * 65];
    __shared__ __align__(16) float Vs[64 * 65];
    __shared__ __align__(16) float Ps[4 * 64 * 20];

    const size_t row_base = (size_t)b * S_;

    #pragma unroll
    for (int r = 0; r < 4; ++r) {
        const int idx4 = tid + (r << 8);
        const int jj = idx4 >> 4;
        const int dd = (idx4 & 15) << 2;
        const float4 v = *(const float4*)(qkv + (row_base + i0 + jj) * 3072 + h * 64 + dd);
        qT[(dd+0)*68 + jj] = v.x;
        qT[(dd+1)*68 + jj] = v.y;
        qT[(dd+2)*68 + jj] = v.z;
        qT[(dd+3)*68 + jj] = v.w;
    }

    float m[16], l[16], acc[16];
    #pragma unroll
    for (int r = 0; r < 16; ++r) { m[r] = NEGINF; l[r] = 0.f; acc[r] = 0.f; }

    for (int kt = 0; kt <= qt; ++kt) {
        const int j0 = kt << 6;
        float4 kf[4], vf[4];
        #pragma unroll
        for (int r = 0; r < 4; ++r) {
            const int idx4 = tid + (r << 8);
            const int jj = idx4 >> 4;
            const int dd = (idx4 & 15) << 2;
            const size_t rp = (row_base + j0 + jj) * 3072 + h * 64 + dd;
            kf[r] = *(const float4*)(qkv + rp + 1024);
            vf[r] = *(const float4*)(qkv + rp + 2048);
        }
        __syncthreads();
        #pragma unroll
        for (int r = 0; r < 4; ++r) {
            const int idx4 = tid + (r << 8);
            const int jj = idx4 >> 4;
            const int dd = (idx4 & 15) << 2;
            Ks[jj*65 + dd+0] = kf[r].x; Ks[jj*65 + dd+1] = kf[r].y;
            Ks[jj*65 + dd+2] = kf[r].z; Ks[jj*65 + dd+3] = kf[r].w;
            Vs[jj*65 + dd+0] = vf[r].x; Vs[jj*65 + dd+1] = vf[r].y;
            Vs[jj*65 + dd+2] = vf[r].z; Vs[jj*65 + dd+3] = vf[r].w;
        }
        __syncthreads();

        float s[16];
        #pragma unroll
        for (int r = 0; r < 16; ++r) s[r] = 0.f;
        const float* kp = &Ks[lane * 65];
        #pragma unroll 2
        for (int d = 0; d < 64; ++d) {
            const float kd = kp[d];
            const float* qd = &qT[d * 68 + r0];
            #pragma unroll
            for (int r4 = 0; r4 < 4; ++r4) {
                const float4 q4 = *(const float4*)(qd + (r4 << 2));
                s[r4*4+0] = fmaf(q4.x, kd, s[r4*4+0]);
                s[r4*4+1] = fmaf(q4.y, kd, s[r4*4+1]);
                s[r4*4+2] = fmaf(q4.z, kd, s[r4*4+2]);
                s[r4*4+3] = fmaf(q4.w, kd, s[r4*4+3]);
            }
        }

        const int j = j0 + lane;
        float p[16];
        #pragma unroll
        for (int r = 0; r < 16; ++r) {
            const int i = i0 + r0 + r;
            float sv = (j <= i) ? fmaf(slope, (float)(j - i), s[r] * 0.125f) : NEGINF;
            float mx = sv;
            #pragma unroll
            for (int o = 32; o; o >>= 1) mx = fmaxf(mx, __shfl_xor(mx, o, 64));
            const float mnew = fmaxf(m[r], mx);
            const float corr = __expf(m[r] - mnew);
            const float pv   = __expf(sv - mnew);
            float ps = pv;
            #pragma unroll
            for (int o = 32; o; o >>= 1) ps += __shfl_xor(ps, o, 64);
            l[r]   = l[r] * corr + ps;
            acc[r] *= corr;
            m[r]   = mnew;
            p[r]   = pv;
        }

        float* pw = &Ps[(wid * 64 + lane) * 20];
        #pragma unroll
        for (int r4 = 0; r4 < 4; ++r4)
            *(float4*)(pw + (r4 << 2)) =
                make_float4(p[r4*4+0], p[r4*4+1], p[r4*4+2], p[r4*4+3]);
        asm volatile("" ::: "memory");

        const float* vp = &Vs[lane];
        const float* pbase = &Ps[wid * 64 * 20];
        #pragma unroll 2
        for (int jj = 0; jj < 64; ++jj) {
            const float vv = vp[jj * 65];
            const float* pj = pbase + jj * 20;
            #pragma unroll
            for (int r4 = 0; r4 < 4; ++r4) {
                const float4 p4 = *(const float4*)(pj + (r4 << 2));
                acc[r4*4+0] = fmaf(p4.x, vv, acc[r4*4+0]);
                acc[r4*4+1] = fmaf(p4.y, vv, acc[r4*4+1]);
                acc[r4*4+2] = fmaf(p4.z, vv, acc[r4*4+2]);
                acc[r4*4+3] = fmaf(p4.w, vv, acc[r4*4+3]);
            }
        }
    }

    #pragma unroll
    for (int r = 0; r < 16; ++r) {
        const int i = i0 + r0 + r;
        ctx[(row_base + i) * D_ + h * 64 + lane] = f2bf_rne(acc[r] / l[r]);
    }
}

// ---------------- launch ----------------------------------------------------------------
extern "C" void kernel_launch(void* const* d_in, const int* in_sizes, int n_in,
                              void* d_out, int out_size, void* d_ws, size_t ws_size,
                              hipStream_t stream) {
    const float* src     = (const float*)d_in[0];
    const float* norm_w  = (const float*)d_in[1];
    const float* norm_b  = (const float*)d_in[2];
    const float* wqkv_w  = (const float*)d_in[3];
    const float* wqkv_b  = (const float*)d_in[4];
    const float* out_w   = (const float*)d_in[5];
    const float* out_b   = (const float*)d_in[6];
    const float* fnorm_w = (const float*)d_in[7];
    const float* fnorm_b = (const float*)d_in[8];
    const float* ff1_w   = (const float*)d_in[9];
    const float* ff1_b   = (const float*)d_in[10];
    const float* ff2_w   = (const float*)d_in[11];
    const float* ff2_b   = (const float*)d_in[12];
    float* out = (float*)d_out;

    const int M = 2 * S_;                 // 4096 rows
    const size_t MB = 1u << 20;
    char* W = (char*)d_ws;
    // [0,6)   wqkvT bf16 [3072][1024]     [6,8)   outT bf16 [1024][1024]
    // [8,16)  ff1T  bf16 [4096][1024]     [16,24) ff2T bf16 [1024][4096]
    // [24,32) h1 bf16 -> reuse as ctx bf16 (h1 dead after QKV GEMM)
    // [32,80) qkv fp32 -> reuse as h2 bf16 [32,40) + ffmid bf16 [40,72) (qkv dead after attn)
    // [80,96) src2 fp32                                      total 96 MB
    unsigned short* wqkvT = (unsigned short*)(W);
    unsigned short* outT  = (unsigned short*)(W + 6  * MB);
    unsigned short* ff1T  = (unsigned short*)(W + 8  * MB);
    unsigned short* ff2T  = (unsigned short*)(W + 16 * MB);
    unsigned short* h1    = (unsigned short*)(W + 24 * MB);
    float*          qkv   = (float*)        (W + 32 * MB);
    unsigned short* ctx   = (unsigned short*)(W + 24 * MB);
    unsigned short* h2    = (unsigned short*)(W + 32 * MB);
    unsigned short* ffmid = (unsigned short*)(W + 40 * MB);
    float*          src2  = (float*)        (W + 80 * MB);

    // weight transpose-casts (fp32 [K][N] -> bf16 [N][K])
    wcast_kernel<<<dim3(3072/64, 1024/64), 256, 0, stream>>>(wqkv_w, wqkvT, 1024, 3072);
    wcast_kernel<<<dim3(1024/64, 1024/64), 256, 0, stream>>>(out_w,  outT,  1024, 1024);
    wcast_kernel<<<dim3(4096/64, 1024/64), 256, 0, stream>>>(ff1_w,  ff1T,  1024, 4096);
    wcast_kernel<<<dim3(1024/64, 4096/64), 256, 0, stream>>>(ff2_w,  ff2T,  4096, 1024);

    // 1) h1 = LN(src) -> bf16
    ln_kernel<true><<<M, 256, 0, stream>>>(src, norm_w, norm_b, h1);
    // 2) qkv = h1 @ wqkv_w + wqkv_b   [4096 x 3072] fp32
    bgemm_kernel<0, false><<<dim3(3072/128, M/128), 256, 0, stream>>>(
        (const __bf16*)h1, (const __bf16*)wqkvT, wqkv_b, nullptr, qkv, M, 3072, 1024);
    // 3) ctx = flash-attn(q,k,v) -> bf16
    attn_kernel<<<2 * H_ * (S_ / 64), 256, 0, stream>>>(qkv, ctx);
    // 4) src2 = src + ctx @ out_w + out_b  fp32
    bgemm_kernel<2, false><<<dim3(1024/128, M/128), 256, 0, stream>>>(
        (const __bf16*)ctx, (const __bf16*)outT, out_b, src, src2, M, 1024, 1024);
    // 5) h2 = LN(src2) -> bf16
    ln_kernel<true><<<M, 256, 0, stream>>>(src2, fnorm_w, fnorm_b, h2);
    // 6) ffmid = relu(h2 @ ff1_w + ff1_b) -> bf16  [4096 x 4096]
    bgemm_kernel<1, true><<<dim3(4096/128, M/128), 256, 0, stream>>>(
        (const __bf16*)h2, (const __bf16*)ff1T, ff1_b, nullptr, ffmid, M, 4096, 1024);
    // 7) out = src2 + ffmid @ ff2_w + ff2_b  fp32
    bgemm_kernel<2, false><<<dim3(1024/128, M/128), 256, 0, stream>>>(
        (const __bf16*)ffmid, (const __bf16*)ff2T, ff2_b, src2, out, M, 1024, 4096);
}

// Round 5
// 423.736 us; speedup vs baseline: 5.5040x; 2.8545x over previous
//
#include <hip/hip_runtime.h>
#include <math.h>

#define S_   2048
#define D_   1024
#define H_   16
#define DFF_ 4096

#define NEGINF (-__builtin_huge_valf())

typedef __bf16 bf16x8 __attribute__((ext_vector_type(8)));
typedef float  f32x4  __attribute__((ext_vector_type(4)));

static __device__ __forceinline__ unsigned short f2bf_rne(float f) {
    unsigned int u = __float_as_uint(f);
    u = (u + 0x7fffu + ((u >> 16) & 1u)) >> 16;
    return (unsigned short)u;
}

// ---------------- LayerNorm: one row (1024 floats) per 256-thread block ----------------
template<bool OBF>
__global__ __launch_bounds__(256) void ln_kernel(
    const float* __restrict__ x, const float* __restrict__ w,
    const float* __restrict__ b, void* __restrict__ y)
{
    const int row = blockIdx.x;
    const int t = threadIdx.x;
    const float4 v = reinterpret_cast<const float4*>(x + (size_t)row * D_)[t];
    float s  = v.x + v.y + v.z + v.w;
    float ss = v.x*v.x + v.y*v.y + v.z*v.z + v.w*v.w;
    #pragma unroll
    for (int o = 32; o; o >>= 1) {
        s  += __shfl_xor(s,  o, 64);
        ss += __shfl_xor(ss, o, 64);
    }
    __shared__ float red[8];
    const int wid = t >> 6, lane = t & 63;
    if (lane == 0) { red[wid] = s; red[4 + wid] = ss; }
    __syncthreads();
    s  = red[0] + red[1] + red[2] + red[3];
    ss = red[4] + red[5] + red[6] + red[7];
    const float mean = s * (1.f / D_);
    const float var  = ss * (1.f / D_) - mean * mean;
    const float rstd = rsqrtf(var + 1e-5f);
    const float4 wv = reinterpret_cast<const float4*>(w)[t];
    const float4 bv = reinterpret_cast<const float4*>(b)[t];
    float4 o;
    o.x = (v.x - mean) * rstd * wv.x + bv.x;
    o.y = (v.y - mean) * rstd * wv.y + bv.y;
    o.z = (v.z - mean) * rstd * wv.z + bv.z;
    o.w = (v.w - mean) * rstd * wv.w + bv.w;
    if (OBF) {
        ushort4 o4;
        o4.x = f2bf_rne(o.x); o4.y = f2bf_rne(o.y);
        o4.z = f2bf_rne(o.z); o4.w = f2bf_rne(o.w);
        reinterpret_cast<ushort4*>((unsigned short*)y + (size_t)row * D_)[t] = o4;
    } else {
        reinterpret_cast<float4*>((float*)y + (size_t)row * D_)[t] = o;
    }
}

// ---------------- Weight transpose + cast: fp32 [K][N] -> bf16 [N][K] ------------------
__global__ __launch_bounds__(256) void wcast_kernel(
    const float* __restrict__ in, unsigned short* __restrict__ outT, int K, int N)
{
    __shared__ float t[64][65];
    const int n0 = blockIdx.x * 64, k0 = blockIdx.y * 64;
    const int tid = threadIdx.x;
    #pragma unroll
    for (int i = 0; i < 16; ++i) {
        const int idx = i * 256 + tid;
        const int kk = idx >> 6, nn = idx & 63;
        t[kk][nn] = in[(size_t)(k0 + kk) * N + n0 + nn];
    }
    __syncthreads();
    #pragma unroll
    for (int i = 0; i < 16; ++i) {
        const int idx = i * 256 + tid;
        const int nn = idx >> 6, kk = idx & 63;
        outT[(size_t)(n0 + nn) * K + k0 + kk] = f2bf_rne(t[kk][nn]);
    }
}

// ---------------- bf16 MFMA GEMM: C[M,N] = A[M,K] @ Bt[N,K]^T (+bias, epi) -------------
template<int EPI, bool OBF>  // EPI 0: +bias  1: +bias,relu  2: +bias,+residual
__global__ __launch_bounds__(256) void bgemm_kernel(
    const __bf16* __restrict__ A,   // [M][K] bf16
    const __bf16* __restrict__ Bt,  // [N][K] bf16 (pre-transposed)
    const float* __restrict__ bias, const float* __restrict__ res,
    void* __restrict__ Cv, int M, int N, int K)
{
    __shared__ __align__(16) __bf16 As[128 * 32];
    __shared__ __align__(16) __bf16 Bs[128 * 32];
    const int tid  = threadIdx.x;
    const int w    = tid >> 6, lane = tid & 63;
    const int wr   = w >> 1, wc = w & 1;
    const int row0 = blockIdx.y * 128, col0 = blockIdx.x * 128;

    const int lrow = lane >> 2;
    const int lchk = (lane & 3) * 8;
    const int frow = lane & 15;
    const int fk   = (lane >> 4) * 8;

    f32x4 acc[4][4] = {};

    for (int kt = 0; kt < K; kt += 32) {
        #pragma unroll
        for (int it = 0; it < 2; ++it) {
            const int arow = w * 32 + it * 16;
            __builtin_amdgcn_global_load_lds(
                (__attribute__((address_space(1))) void*)(A + (size_t)(row0 + arow + lrow) * K + kt + lchk),
                (__attribute__((address_space(3))) void*)(&As[arow * 32]), 16, 0, 0);
            __builtin_amdgcn_global_load_lds(
                (__attribute__((address_space(1))) void*)(Bt + (size_t)(col0 + arow + lrow) * K + kt + lchk),
                (__attribute__((address_space(3))) void*)(&Bs[arow * 32]), 16, 0, 0);
        }
        __syncthreads();
        bf16x8 af[4], bfr[4];
        #pragma unroll
        for (int i = 0; i < 4; ++i) {
            af[i]  = *(const bf16x8*)&As[(wr * 64 + i * 16 + frow) * 32 + fk];
            bfr[i] = *(const bf16x8*)&Bs[(wc * 64 + i * 16 + frow) * 32 + fk];
        }
        #pragma unroll
        for (int mi = 0; mi < 4; ++mi)
            #pragma unroll
            for (int ni = 0; ni < 4; ++ni)
                acc[mi][ni] = __builtin_amdgcn_mfma_f32_16x16x32_bf16(
                    af[mi], bfr[ni], acc[mi][ni], 0, 0, 0);
        __syncthreads();
    }

    float bz[4];
    #pragma unroll
    for (int ni = 0; ni < 4; ++ni) bz[ni] = bias[col0 + wc * 64 + ni * 16 + frow];
    #pragma unroll
    for (int mi = 0; mi < 4; ++mi) {
        #pragma unroll
        for (int j = 0; j < 4; ++j) {
            const int row = row0 + wr * 64 + mi * 16 + (lane >> 4) * 4 + j;
            #pragma unroll
            for (int ni = 0; ni < 4; ++ni) {
                const int col = col0 + wc * 64 + ni * 16 + frow;
                float v = acc[mi][ni][j] + bz[ni];
                if (EPI == 1) v = fmaxf(v, 0.f);
                if (EPI == 2) v += res[(size_t)row * N + col];
                if (OBF) ((unsigned short*)Cv)[(size_t)row * N + col] = f2bf_rne(v);
                else     ((float*)Cv)[(size_t)row * N + col] = v;
            }
        }
    }
}

// ---------------- bf16 MFMA flash attention with ALiBi, causal -------------------------
// Grid: B*H*16 = 512 blocks; block does q-tiles {qt, 31-qt} -> uniform 33 kv-steps.
// 4 waves x 16 q-rows. Per kv-step/wave: 8 MFMA QK^T + 8 MFMA PV (16x16x32 bf16).
// K staged [key][d] stride 72 (B-operand direct); V staged transposed [d][key] with
// chunk-XOR swizzle (conflict-free b128 reads, ~2-way writes); P restaged per-wave
// (C-layout -> A-layout). Next tile's K/V global loads issued before current compute.
__global__ __launch_bounds__(256) void attn_kernel(
    const __bf16* __restrict__ qkv, __bf16* __restrict__ ctx)
{
    const int pair = blockIdx.x & 15;
    const int bh   = blockIdx.x >> 4;
    const int b    = bh >> 4, h = bh & 15;
    const int tid  = threadIdx.x;
    const int wid  = tid >> 6, lane = tid & 63;
    const int l15  = lane & 15, l4 = lane >> 4;
    const float slope = exp2f(-(float)h);
    const size_t rowb = (size_t)b * S_;

    __shared__ __align__(16) __bf16 Ks[64 * 72];
    __shared__ __align__(16) __bf16 Vt[64 * 72];
    __shared__ __align__(16) __bf16 Ps[4 * 16 * 72];

    const int jr = tid >> 3;   // staging row 0..31 (and +32)
    const int c  = tid & 7;    // staging chunk
    const int c8 = c * 8;
    __bf16* psw = &Ps[wid * 16 * 72];
    const __bf16* base = qkv + rowb * 3072 + h * 64;

    #pragma unroll 1
    for (int half = 0; half < 2; ++half) {
        const int qt = half ? 31 - pair : pair;
        const int i0 = qt << 6;

        bf16x8 qf[2];
        {
            const __bf16* qp = base + (size_t)(i0 + wid * 16 + l15) * 3072 + l4 * 8;
            qf[0] = *(const bf16x8*)(qp);
            qf[1] = *(const bf16x8*)(qp + 32);
        }

        float m[4], l[4];
        f32x4 acc[4];
        #pragma unroll
        for (int j = 0; j < 4; ++j) { m[j] = NEGINF; l[j] = 0.f; }
        #pragma unroll
        for (int ni = 0; ni < 4; ++ni) acc[ni] = (f32x4){0.f, 0.f, 0.f, 0.f};

        bf16x8 k0, k1, v0, v1;
        {   // prefetch tile 0
            const __bf16* kvp = base + (size_t)jr * 3072;
            k0 = *(const bf16x8*)(kvp + 1024 + c8);
            v0 = *(const bf16x8*)(kvp + 2048 + c8);
            k1 = *(const bf16x8*)(kvp + 32 * 3072 + 1024 + c8);
            v1 = *(const bf16x8*)(kvp + 32 * 3072 + 2048 + c8);
        }

        for (int kt = 0; kt <= qt; ++kt) {
            __syncthreads();               // previous tile's LDS reads complete
            *(bf16x8*)&Ks[jr * 72 + c8]        = k0;
            *(bf16x8*)&Ks[(jr + 32) * 72 + c8] = k1;
            // Vt: elem (key j, dim d) at Vt[d*72 + ((j>>3 ^ d>>3)&7)*8 + (j&7)]
            const int sw0 = (((jr >> 3) ^ c) & 7) * 8 + (jr & 7);
            const int sw1 = ((((jr + 32) >> 3) ^ c) & 7) * 8 + (jr & 7);
            #pragma unroll
            for (int e = 0; e < 8; ++e) {
                Vt[(c8 + e) * 72 + sw0] = v0[e];
                Vt[(c8 + e) * 72 + sw1] = v1[e];
            }
            __syncthreads();

            if (kt < qt) {                 // issue next tile's loads early (hide latency)
                const __bf16* kvp = base + (size_t)(((kt + 1) << 6) + jr) * 3072;
                k0 = *(const bf16x8*)(kvp + 1024 + c8);
                v0 = *(const bf16x8*)(kvp + 2048 + c8);
                k1 = *(const bf16x8*)(kvp + 32 * 3072 + 1024 + c8);
                v1 = *(const bf16x8*)(kvp + 32 * 3072 + 2048 + c8);
            }

            // ---- QK^T: S[16 q][64 k]
            f32x4 sf[4];
            #pragma unroll
            for (int ni = 0; ni < 4; ++ni) sf[ni] = (f32x4){0.f, 0.f, 0.f, 0.f};
            #pragma unroll
            for (int kd = 0; kd < 2; ++kd)
                #pragma unroll
                for (int ni = 0; ni < 4; ++ni) {
                    const bf16x8 bf = *(const bf16x8*)&Ks[(ni * 16 + l15) * 72 + kd * 32 + l4 * 8];
                    sf[ni] = __builtin_amdgcn_mfma_f32_16x16x32_bf16(qf[kd], bf, sf[ni], 0, 0, 0);
                }

            // ---- bias + mask (C layout: row = l4*4+j, col = ni*16+l15)
            float pv[4][4];
            const int j0 = kt << 6;
            if (kt == qt) {
                #pragma unroll
                for (int ni = 0; ni < 4; ++ni) {
                    const int jcol = ni * 16 + l15;
                    #pragma unroll
                    for (int j = 0; j < 4; ++j) {
                        const int iloc = wid * 16 + l4 * 4 + j;
                        pv[ni][j] = (jcol <= iloc)
                            ? fmaf(slope, (float)(jcol - iloc), sf[ni][j] * 0.125f)
                            : NEGINF;
                    }
                }
            } else {
                const float dbase = (float)(j0 - i0);
                #pragma unroll
                for (int ni = 0; ni < 4; ++ni) {
                    const int jcol = ni * 16 + l15;
                    #pragma unroll
                    for (int j = 0; j < 4; ++j) {
                        const int iloc = wid * 16 + l4 * 4 + j;
                        pv[ni][j] = fmaf(slope, dbase + (float)(jcol - iloc), sf[ni][j] * 0.125f);
                    }
                }
            }

            // ---- online softmax: rows live in 16-lane groups -> shfl_xor 1,2,4,8
            #pragma unroll
            for (int j = 0; j < 4; ++j) {
                float mx = fmaxf(fmaxf(pv[0][j], pv[1][j]), fmaxf(pv[2][j], pv[3][j]));
                mx = fmaxf(mx, __shfl_xor(mx, 1, 64));
                mx = fmaxf(mx, __shfl_xor(mx, 2, 64));
                mx = fmaxf(mx, __shfl_xor(mx, 4, 64));
                mx = fmaxf(mx, __shfl_xor(mx, 8, 64));
                const float mnew = fmaxf(m[j], mx);
                const float corr = __expf(m[j] - mnew);
                float s0 = 0.f;
                #pragma unroll
                for (int ni = 0; ni < 4; ++ni) {
                    const float e = __expf(pv[ni][j] - mnew);
                    pv[ni][j] = e;
                    s0 += e;
                }
                s0 += __shfl_xor(s0, 1, 64);
                s0 += __shfl_xor(s0, 2, 64);
                s0 += __shfl_xor(s0, 4, 64);
                s0 += __shfl_xor(s0, 8, 64);
                l[j] = l[j] * corr + s0;
                m[j] = mnew;
                #pragma unroll
                for (int ni = 0; ni < 4; ++ni) acc[ni][j] *= corr;
            }

            // ---- stage P (per-wave; C-layout -> A-layout via LDS)
            #pragma unroll
            for (int ni = 0; ni < 4; ++ni)
                #pragma unroll
                for (int j = 0; j < 4; ++j)
                    psw[(l4 * 4 + j) * 72 + ni * 16 + l15] = (__bf16)pv[ni][j];
            asm volatile("" ::: "memory");

            // ---- PV: ctx[16 q][64 d] += P @ V
            #pragma unroll
            for (int kk = 0; kk < 2; ++kk) {
                const bf16x8 pa = *(const bf16x8*)&psw[l15 * 72 + kk * 32 + l4 * 8];
                #pragma unroll
                for (int ni = 0; ni < 4; ++ni) {
                    const int d = ni * 16 + l15;
                    const int pc = ((kk * 4 + l4) ^ (d >> 3)) & 7;
                    const bf16x8 bv = *(const bf16x8*)&Vt[d * 72 + pc * 8];
                    acc[ni] = __builtin_amdgcn_mfma_f32_16x16x32_bf16(pa, bv, acc[ni], 0, 0, 0);
                }
            }
        }

        // ---- epilogue
        #pragma unroll
        for (int ni = 0; ni < 4; ++ni) {
            const int col = h * 64 + ni * 16 + l15;
            #pragma unroll
            for (int j = 0; j < 4; ++j) {
                const int row = i0 + wid * 16 + l4 * 4 + j;
                ctx[(rowb + row) * (size_t)D_ + col] = (__bf16)(acc[ni][j] / l[j]);
            }
        }
    }
}

// ---------------- launch ----------------------------------------------------------------
extern "C" void kernel_launch(void* const* d_in, const int* in_sizes, int n_in,
                              void* d_out, int out_size, void* d_ws, size_t ws_size,
                              hipStream_t stream) {
    const float* src     = (const float*)d_in[0];
    const float* norm_w  = (const float*)d_in[1];
    const float* norm_b  = (const float*)d_in[2];
    const float* wqkv_w  = (const float*)d_in[3];
    const float* wqkv_b  = (const float*)d_in[4];
    const float* out_w   = (const float*)d_in[5];
    const float* out_b   = (const float*)d_in[6];
    const float* fnorm_w = (const float*)d_in[7];
    const float* fnorm_b = (const float*)d_in[8];
    const float* ff1_w   = (const float*)d_in[9];
    const float* ff1_b   = (const float*)d_in[10];
    const float* ff2_w   = (const float*)d_in[11];
    const float* ff2_b   = (const float*)d_in[12];
    float* out = (float*)d_out;

    const int M = 2 * S_;
    const size_t MB = 1u << 20;
    char* W = (char*)d_ws;
    // [0,6) wqkvT | [6,8) outT | [8,16) ff1T | [16,24) ff2T   (bf16 weights)
    // [24,32) h1 bf16 -> reuse as ctx bf16
    // [32,56) qkv bf16 -> reuse as h2 bf16 [32,40) + ffmid bf16 [40,72)
    // [80,96) src2 fp32
    unsigned short* wqkvT = (unsigned short*)(W);
    unsigned short* outT  = (unsigned short*)(W + 6  * MB);
    unsigned short* ff1T  = (unsigned short*)(W + 8  * MB);
    unsigned short* ff2T  = (unsigned short*)(W + 16 * MB);
    unsigned short* h1    = (unsigned short*)(W + 24 * MB);
    unsigned short* qkv   = (unsigned short*)(W + 32 * MB);
    unsigned short* ctx   = (unsigned short*)(W + 24 * MB);
    unsigned short* h2    = (unsigned short*)(W + 32 * MB);
    unsigned short* ffmid = (unsigned short*)(W + 40 * MB);
    float*          src2  = (float*)        (W + 80 * MB);

    wcast_kernel<<<dim3(3072/64, 1024/64), 256, 0, stream>>>(wqkv_w, wqkvT, 1024, 3072);
    wcast_kernel<<<dim3(1024/64, 1024/64), 256, 0, stream>>>(out_w,  outT,  1024, 1024);
    wcast_kernel<<<dim3(4096/64, 1024/64), 256, 0, stream>>>(ff1_w,  ff1T,  1024, 4096);
    wcast_kernel<<<dim3(1024/64, 4096/64), 256, 0, stream>>>(ff2_w,  ff2T,  4096, 1024);

    // 1) h1 = LN(src) -> bf16
    ln_kernel<true><<<M, 256, 0, stream>>>(src, norm_w, norm_b, h1);
    // 2) qkv = h1 @ wqkv_w + wqkv_b -> bf16  [4096 x 3072]
    bgemm_kernel<0, true><<<dim3(3072/128, M/128), 256, 0, stream>>>(
        (const __bf16*)h1, (const __bf16*)wqkvT, wqkv_b, nullptr, qkv, M, 3072, 1024);
    // 3) ctx = flash-attn(q,k,v) -> bf16
    attn_kernel<<<2 * H_ * 16, 256, 0, stream>>>((const __bf16*)qkv, (__bf16*)ctx);
    // 4) src2 = src + ctx @ out_w + out_b  fp32
    bgemm_kernel<2, false><<<dim3(1024/128, M/128), 256, 0, stream>>>(
        (const __bf16*)ctx, (const __bf16*)outT, out_b, src, src2, M, 1024, 1024);
    // 5) h2 = LN(src2) -> bf16
    ln_kernel<true><<<M, 256, 0, stream>>>(src2, fnorm_w, fnorm_b, h2);
    // 6) ffmid = relu(h2 @ ff1_w + ff1_b) -> bf16  [4096 x 4096]
    bgemm_kernel<1, true><<<dim3(4096/128, M/128), 256, 0, stream>>>(
        (const __bf16*)h2, (const __bf16*)ff1T, ff1_b, nullptr, ffmid, M, 4096, 1024);
    // 7) out = src2 + ffmid @ ff2_w + ff2_b  fp32
    bgemm_kernel<2, false><<<dim3(1024/128, M/128), 256, 0, stream>>>(
        (const __bf16*)ffmid, (const __bf16*)ff2T, ff2_b, src2, out, M, 1024, 4096);
}

// Round 6
// 411.119 us; speedup vs baseline: 5.6729x; 1.0307x over previous
//
#include <hip/hip_runtime.h>
#include <math.h>

#define S_   2048
#define D_   1024
#define H_   16
#define DFF_ 4096

#define NEGINF (-__builtin_huge_valf())

typedef __bf16 bf16x8 __attribute__((ext_vector_type(8)));
typedef float  f32x4  __attribute__((ext_vector_type(4)));

static __device__ __forceinline__ unsigned short f2bf_rne(float f) {
    unsigned int u = __float_as_uint(f);
    u = (u + 0x7fffu + ((u >> 16) & 1u)) >> 16;
    return (unsigned short)u;
}

// ---------------- LayerNorm: one row (1024 floats) per 256-thread block ----------------
template<bool OBF>
__global__ __launch_bounds__(256) void ln_kernel(
    const float* __restrict__ x, const float* __restrict__ w,
    const float* __restrict__ b, void* __restrict__ y)
{
    const int row = blockIdx.x;
    const int t = threadIdx.x;
    const float4 v = reinterpret_cast<const float4*>(x + (size_t)row * D_)[t];
    float s  = v.x + v.y + v.z + v.w;
    float ss = v.x*v.x + v.y*v.y + v.z*v.z + v.w*v.w;
    #pragma unroll
    for (int o = 32; o; o >>= 1) {
        s  += __shfl_xor(s,  o, 64);
        ss += __shfl_xor(ss, o, 64);
    }
    __shared__ float red[8];
    const int wid = t >> 6, lane = t & 63;
    if (lane == 0) { red[wid] = s; red[4 + wid] = ss; }
    __syncthreads();
    s  = red[0] + red[1] + red[2] + red[3];
    ss = red[4] + red[5] + red[6] + red[7];
    const float mean = s * (1.f / D_);
    const float var  = ss * (1.f / D_) - mean * mean;
    const float rstd = rsqrtf(var + 1e-5f);
    const float4 wv = reinterpret_cast<const float4*>(w)[t];
    const float4 bv = reinterpret_cast<const float4*>(b)[t];
    float4 o;
    o.x = (v.x - mean) * rstd * wv.x + bv.x;
    o.y = (v.y - mean) * rstd * wv.y + bv.y;
    o.z = (v.z - mean) * rstd * wv.z + bv.z;
    o.w = (v.w - mean) * rstd * wv.w + bv.w;
    if (OBF) {
        ushort4 o4;
        o4.x = f2bf_rne(o.x); o4.y = f2bf_rne(o.y);
        o4.z = f2bf_rne(o.z); o4.w = f2bf_rne(o.w);
        reinterpret_cast<ushort4*>((unsigned short*)y + (size_t)row * D_)[t] = o4;
    } else {
        reinterpret_cast<float4*>((float*)y + (size_t)row * D_)[t] = o;
    }
}

// ---------------- Weight transpose + cast: fp32 [K][N] -> bf16 [N][K] ------------------
__global__ __launch_bounds__(256) void wcast_kernel(
    const float* __restrict__ in, unsigned short* __restrict__ outT, int K, int N)
{
    __shared__ float t[64][65];
    const int n0 = blockIdx.x * 64, k0 = blockIdx.y * 64;
    const int tid = threadIdx.x;
    #pragma unroll
    for (int i = 0; i < 16; ++i) {
        const int idx = i * 256 + tid;
        const int kk = idx >> 6, nn = idx & 63;
        t[kk][nn] = in[(size_t)(k0 + kk) * N + n0 + nn];
    }
    __syncthreads();
    #pragma unroll
    for (int i = 0; i < 16; ++i) {
        const int idx = i * 256 + tid;
        const int nn = idx >> 6, kk = idx & 63;
        outT[(size_t)(n0 + nn) * K + k0 + kk] = f2bf_rne(t[kk][nn]);
    }
}

// ---------------- bf16 MFMA GEMM: C[M,N] = A[M,K] @ Bt[N,K]^T (+bias, epi) -------------
// 128x128 tile, BK=64, 256 threads = 4 waves, each wave a 64x64 quadrant (4x4 frags,
// 2 k-chunks -> 32 MFMA per barrier-pair). LDS linear for global_load_lds; the global
// SOURCE 16B-chunk is swizzled (chunk ^= row&7, stays in the same 128B segment) and
// fragment reads apply the same involution -> 2-way banks (free). 1D grid with
// bijective XCD swizzle (all grids %8==0) for per-XCD L2 A-panel locality.
template<int EPI, bool OBF>  // EPI 0: +bias  1: +bias,relu  2: +bias,+residual
__global__ __launch_bounds__(256) void bgemm_kernel(
    const __bf16* __restrict__ A,   // [M][K] bf16
    const __bf16* __restrict__ Bt,  // [N][K] bf16 (pre-transposed)
    const float* __restrict__ bias, const float* __restrict__ res,
    void* __restrict__ Cv, int M, int N, int K)
{
    __shared__ __align__(16) __bf16 As[128 * 64];
    __shared__ __align__(16) __bf16 Bs[128 * 64];
    const int tid  = threadIdx.x;
    const int w    = tid >> 6, lane = tid & 63;
    const int wr   = w >> 1, wc = w & 1;

    // XCD-aware bijective remap of the 1D block id (nwg % 8 == 0 for all our shapes)
    const int nwg  = gridDim.x;
    const int lin  = blockIdx.x;
    const int wg   = (lin & 7) * (nwg >> 3) + (lin >> 3);
    const int gridN = N >> 7;
    const int row0 = (wg / gridN) << 7;
    const int col0 = (wg % gridN) << 7;

    const int srow = lane >> 3;             // staging: row within 8-row chunk
    const int scol = ((lane & 7) ^ srow) << 3;  // swizzled source col (bf16 units)
    const int frow = lane & 15;             // fragment row/col within 16x16
    const int l4   = lane >> 4;             // fragment k-group (0..3)
    const int r7   = frow & 7;              // read-side swizzle key

    f32x4 acc[4][4] = {};

    for (int kt = 0; kt < K; kt += 64) {
        #pragma unroll
        for (int it = 0; it < 4; ++it) {
            const int arow = w * 32 + it * 8;   // wave-uniform
            __builtin_amdgcn_global_load_lds(
                (__attribute__((address_space(1))) void*)(A + (size_t)(row0 + arow + srow) * K + kt + scol),
                (__attribute__((address_space(3))) void*)(&As[arow * 64]), 16, 0, 0);
            __builtin_amdgcn_global_load_lds(
                (__attribute__((address_space(1))) void*)(Bt + (size_t)(col0 + arow + srow) * K + kt + scol),
                (__attribute__((address_space(3))) void*)(&Bs[arow * 64]), 16, 0, 0);
        }
        __syncthreads();   // drains vmcnt; also protects prev iteration's LDS reads
        #pragma unroll
        for (int kk = 0; kk < 2; ++kk) {
            const int ch = ((kk * 4 + l4) ^ r7) * 8;   // swizzled chunk offset
            bf16x8 af[4], bfr[4];
            #pragma unroll
            for (int i = 0; i < 4; ++i) {
                af[i]  = *(const bf16x8*)&As[(wr * 64 + i * 16 + frow) * 64 + ch];
                bfr[i] = *(const bf16x8*)&Bs[(wc * 64 + i * 16 + frow) * 64 + ch];
            }
            #pragma unroll
            for (int mi = 0; mi < 4; ++mi)
                #pragma unroll
                for (int ni = 0; ni < 4; ++ni)
                    acc[mi][ni] = __builtin_amdgcn_mfma_f32_16x16x32_bf16(
                        af[mi], bfr[ni], acc[mi][ni], 0, 0, 0);
        }
        __syncthreads();
    }

    // epilogue: C/D layout col = lane&15, row = (lane>>4)*4 + reg
    float bz[4];
    #pragma unroll
    for (int ni = 0; ni < 4; ++ni) bz[ni] = bias[col0 + wc * 64 + ni * 16 + frow];
    #pragma unroll
    for (int mi = 0; mi < 4; ++mi) {
        #pragma unroll
        for (int j = 0; j < 4; ++j) {
            const int row = row0 + wr * 64 + mi * 16 + l4 * 4 + j;
            #pragma unroll
            for (int ni = 0; ni < 4; ++ni) {
                const int col = col0 + wc * 64 + ni * 16 + frow;
                float v = acc[mi][ni][j] + bz[ni];
                if (EPI == 1) v = fmaxf(v, 0.f);
                if (EPI == 2) v += res[(size_t)row * N + col];
                if (OBF) ((unsigned short*)Cv)[(size_t)row * N + col] = f2bf_rne(v);
                else     ((float*)Cv)[(size_t)row * N + col] = v;
            }
        }
    }
}

// ---------------- bf16 MFMA flash attention with ALiBi, causal -------------------------
__global__ __launch_bounds__(256) void attn_kernel(
    const __bf16* __restrict__ qkv, __bf16* __restrict__ ctx)
{
    const int pair = blockIdx.x & 15;
    const int bh   = blockIdx.x >> 4;
    const int b    = bh >> 4, h = bh & 15;
    const int tid  = threadIdx.x;
    const int wid  = tid >> 6, lane = tid & 63;
    const int l15  = lane & 15, l4 = lane >> 4;
    const float slope = exp2f(-(float)h);
    const size_t rowb = (size_t)b * S_;

    __shared__ __align__(16) __bf16 Ks[64 * 72];
    __shared__ __align__(16) __bf16 Vt[64 * 72];
    __shared__ __align__(16) __bf16 Ps[4 * 16 * 72];

    const int jr = tid >> 3;
    const int c  = tid & 7;
    const int c8 = c * 8;
    __bf16* psw = &Ps[wid * 16 * 72];
    const __bf16* base = qkv + rowb * 3072 + h * 64;

    #pragma unroll 1
    for (int half = 0; half < 2; ++half) {
        const int qt = half ? 31 - pair : pair;
        const int i0 = qt << 6;

        bf16x8 qf[2];
        {
            const __bf16* qp = base + (size_t)(i0 + wid * 16 + l15) * 3072 + l4 * 8;
            qf[0] = *(const bf16x8*)(qp);
            qf[1] = *(const bf16x8*)(qp + 32);
        }

        float m[4], l[4];
        f32x4 acc[4];
        #pragma unroll
        for (int j = 0; j < 4; ++j) { m[j] = NEGINF; l[j] = 0.f; }
        #pragma unroll
        for (int ni = 0; ni < 4; ++ni) acc[ni] = (f32x4){0.f, 0.f, 0.f, 0.f};

        bf16x8 k0, k1, v0, v1;
        {
            const __bf16* kvp = base + (size_t)jr * 3072;
            k0 = *(const bf16x8*)(kvp + 1024 + c8);
            v0 = *(const bf16x8*)(kvp + 2048 + c8);
            k1 = *(const bf16x8*)(kvp + 32 * 3072 + 1024 + c8);
            v1 = *(const bf16x8*)(kvp + 32 * 3072 + 2048 + c8);
        }

        for (int kt = 0; kt <= qt; ++kt) {
            __syncthreads();
            *(bf16x8*)&Ks[jr * 72 + c8]        = k0;
            *(bf16x8*)&Ks[(jr + 32) * 72 + c8] = k1;
            const int sw0 = (((jr >> 3) ^ c) & 7) * 8 + (jr & 7);
            const int sw1 = ((((jr + 32) >> 3) ^ c) & 7) * 8 + (jr & 7);
            #pragma unroll
            for (int e = 0; e < 8; ++e) {
                Vt[(c8 + e) * 72 + sw0] = v0[e];
                Vt[(c8 + e) * 72 + sw1] = v1[e];
            }
            __syncthreads();

            if (kt < qt) {
                const __bf16* kvp = base + (size_t)(((kt + 1) << 6) + jr) * 3072;
                k0 = *(const bf16x8*)(kvp + 1024 + c8);
                v0 = *(const bf16x8*)(kvp + 2048 + c8);
                k1 = *(const bf16x8*)(kvp + 32 * 3072 + 1024 + c8);
                v1 = *(const bf16x8*)(kvp + 32 * 3072 + 2048 + c8);
            }

            f32x4 sf[4];
            #pragma unroll
            for (int ni = 0; ni < 4; ++ni) sf[ni] = (f32x4){0.f, 0.f, 0.f, 0.f};
            #pragma unroll
            for (int kd = 0; kd < 2; ++kd)
                #pragma unroll
                for (int ni = 0; ni < 4; ++ni) {
                    const bf16x8 bf = *(const bf16x8*)&Ks[(ni * 16 + l15) * 72 + kd * 32 + l4 * 8];
                    sf[ni] = __builtin_amdgcn_mfma_f32_16x16x32_bf16(qf[kd], bf, sf[ni], 0, 0, 0);
                }

            float pv[4][4];
            const int j0 = kt << 6;
            if (kt == qt) {
                #pragma unroll
                for (int ni = 0; ni < 4; ++ni) {
                    const int jcol = ni * 16 + l15;
                    #pragma unroll
                    for (int j = 0; j < 4; ++j) {
                        const int iloc = wid * 16 + l4 * 4 + j;
                        pv[ni][j] = (jcol <= iloc)
                            ? fmaf(slope, (float)(jcol - iloc), sf[ni][j] * 0.125f)
                            : NEGINF;
                    }
                }
            } else {
                const float dbase = (float)(j0 - i0);
                #pragma unroll
                for (int ni = 0; ni < 4; ++ni) {
                    const int jcol = ni * 16 + l15;
                    #pragma unroll
                    for (int j = 0; j < 4; ++j) {
                        const int iloc = wid * 16 + l4 * 4 + j;
                        pv[ni][j] = fmaf(slope, dbase + (float)(jcol - iloc), sf[ni][j] * 0.125f);
                    }
                }
            }

            #pragma unroll
            for (int j = 0; j < 4; ++j) {
                float mx = fmaxf(fmaxf(pv[0][j], pv[1][j]), fmaxf(pv[2][j], pv[3][j]));
                mx = fmaxf(mx, __shfl_xor(mx, 1, 64));
                mx = fmaxf(mx, __shfl_xor(mx, 2, 64));
                mx = fmaxf(mx, __shfl_xor(mx, 4, 64));
                mx = fmaxf(mx, __shfl_xor(mx, 8, 64));
                const float mnew = fmaxf(m[j], mx);
                const float corr = __expf(m[j] - mnew);
                float s0 = 0.f;
                #pragma unroll
                for (int ni = 0; ni < 4; ++ni) {
                    const float e = __expf(pv[ni][j] - mnew);
                    pv[ni][j] = e;
                    s0 += e;
                }
                s0 += __shfl_xor(s0, 1, 64);
                s0 += __shfl_xor(s0, 2, 64);
                s0 += __shfl_xor(s0, 4, 64);
                s0 += __shfl_xor(s0, 8, 64);
                l[j] = l[j] * corr + s0;
                m[j] = mnew;
                #pragma unroll
                for (int ni = 0; ni < 4; ++ni) acc[ni][j] *= corr;
            }

            #pragma unroll
            for (int ni = 0; ni < 4; ++ni)
                #pragma unroll
                for (int j = 0; j < 4; ++j)
                    psw[(l4 * 4 + j) * 72 + ni * 16 + l15] = (__bf16)pv[ni][j];
            asm volatile("" ::: "memory");

            #pragma unroll
            for (int kk = 0; kk < 2; ++kk) {
                const bf16x8 pa = *(const bf16x8*)&psw[l15 * 72 + kk * 32 + l4 * 8];
                #pragma unroll
                for (int ni = 0; ni < 4; ++ni) {
                    const int d = ni * 16 + l15;
                    const int pc = ((kk * 4 + l4) ^ (d >> 3)) & 7;
                    const bf16x8 bv = *(const bf16x8*)&Vt[d * 72 + pc * 8];
                    acc[ni] = __builtin_amdgcn_mfma_f32_16x16x32_bf16(pa, bv, acc[ni], 0, 0, 0);
                }
            }
        }

        #pragma unroll
        for (int ni = 0; ni < 4; ++ni) {
            const int col = h * 64 + ni * 16 + l15;
            #pragma unroll
            for (int j = 0; j < 4; ++j) {
                const int row = i0 + wid * 16 + l4 * 4 + j;
                ctx[(rowb + row) * (size_t)D_ + col] = (__bf16)(acc[ni][j] / l[j]);
            }
        }
    }
}

// ---------------- launch ----------------------------------------------------------------
extern "C" void kernel_launch(void* const* d_in, const int* in_sizes, int n_in,
                              void* d_out, int out_size, void* d_ws, size_t ws_size,
                              hipStream_t stream) {
    const float* src     = (const float*)d_in[0];
    const float* norm_w  = (const float*)d_in[1];
    const float* norm_b  = (const float*)d_in[2];
    const float* wqkv_w  = (const float*)d_in[3];
    const float* wqkv_b  = (const float*)d_in[4];
    const float* out_w   = (const float*)d_in[5];
    const float* out_b   = (const float*)d_in[6];
    const float* fnorm_w = (const float*)d_in[7];
    const float* fnorm_b = (const float*)d_in[8];
    const float* ff1_w   = (const float*)d_in[9];
    const float* ff1_b   = (const float*)d_in[10];
    const float* ff2_w   = (const float*)d_in[11];
    const float* ff2_b   = (const float*)d_in[12];
    float* out = (float*)d_out;

    const int M = 2 * S_;
    const size_t MB = 1u << 20;
    char* W = (char*)d_ws;
    unsigned short* wqkvT = (unsigned short*)(W);
    unsigned short* outT  = (unsigned short*)(W + 6  * MB);
    unsigned short* ff1T  = (unsigned short*)(W + 8  * MB);
    unsigned short* ff2T  = (unsigned short*)(W + 16 * MB);
    unsigned short* h1    = (unsigned short*)(W + 24 * MB);
    unsigned short* qkv   = (unsigned short*)(W + 32 * MB);
    unsigned short* ctx   = (unsigned short*)(W + 24 * MB);
    unsigned short* h2    = (unsigned short*)(W + 32 * MB);
    unsigned short* ffmid = (unsigned short*)(W + 40 * MB);
    float*          src2  = (float*)        (W + 80 * MB);

    wcast_kernel<<<dim3(3072/64, 1024/64), 256, 0, stream>>>(wqkv_w, wqkvT, 1024, 3072);
    wcast_kernel<<<dim3(1024/64, 1024/64), 256, 0, stream>>>(out_w,  outT,  1024, 1024);
    wcast_kernel<<<dim3(4096/64, 1024/64), 256, 0, stream>>>(ff1_w,  ff1T,  1024, 4096);
    wcast_kernel<<<dim3(1024/64, 4096/64), 256, 0, stream>>>(ff2_w,  ff2T,  4096, 1024);

    // 1) h1 = LN(src) -> bf16
    ln_kernel<true><<<M, 256, 0, stream>>>(src, norm_w, norm_b, h1);
    // 2) qkv = h1 @ wqkv_w + wqkv_b -> bf16  [4096 x 3072]  (768 blocks)
    bgemm_kernel<0, true><<<(3072/128) * (M/128), 256, 0, stream>>>(
        (const __bf16*)h1, (const __bf16*)wqkvT, wqkv_b, nullptr, qkv, M, 3072, 1024);
    // 3) ctx = flash-attn(q,k,v) -> bf16
    attn_kernel<<<2 * H_ * 16, 256, 0, stream>>>((const __bf16*)qkv, (__bf16*)ctx);
    // 4) src2 = src + ctx @ out_w + out_b  fp32  (256 blocks)
    bgemm_kernel<2, false><<<(1024/128) * (M/128), 256, 0, stream>>>(
        (const __bf16*)ctx, (const __bf16*)outT, out_b, src, src2, M, 1024, 1024);
    // 5) h2 = LN(src2) -> bf16
    ln_kernel<true><<<M, 256, 0, stream>>>(src2, fnorm_w, fnorm_b, h2);
    // 6) ffmid = relu(h2 @ ff1_w + ff1_b) -> bf16  [4096 x 4096]  (1024 blocks)
    bgemm_kernel<1, true><<<(4096/128) * (M/128), 256, 0, stream>>>(
        (const __bf16*)h2, (const __bf16*)ff1T, ff1_b, nullptr, ffmid, M, 4096, 1024);
    // 7) out = src2 + ffmid @ ff2_w + ff2_b  fp32  (256 blocks)
    bgemm_kernel<2, false><<<(1024/128) * (M/128), 256, 0, stream>>>(
        (const __bf16*)ffmid, (const __bf16*)ff2T, ff2_b, src2, out, M, 1024, 4096);
}

// Round 7
// 394.573 us; speedup vs baseline: 5.9108x; 1.0419x over previous
//
#include <hip/hip_runtime.h>
#include <math.h>

#define S_   2048
#define D_   1024
#define H_   16
#define DFF_ 4096

#define NEGINF (-__builtin_huge_valf())

typedef __bf16 bf16x8 __attribute__((ext_vector_type(8)));
typedef float  f32x4  __attribute__((ext_vector_type(4)));

static __device__ __forceinline__ unsigned short f2bf_rne(float f) {
    unsigned int u = __float_as_uint(f);
    u = (u + 0x7fffu + ((u >> 16) & 1u)) >> 16;
    return (unsigned short)u;
}

// ---------------- LayerNorm: one row (1024 floats) per 256-thread block ----------------
template<bool OBF>
__global__ __launch_bounds__(256) void ln_kernel(
    const float* __restrict__ x, const float* __restrict__ w,
    const float* __restrict__ b, void* __restrict__ y)
{
    const int row = blockIdx.x;
    const int t = threadIdx.x;
    const float4 v = reinterpret_cast<const float4*>(x + (size_t)row * D_)[t];
    float s  = v.x + v.y + v.z + v.w;
    float ss = v.x*v.x + v.y*v.y + v.z*v.z + v.w*v.w;
    #pragma unroll
    for (int o = 32; o; o >>= 1) {
        s  += __shfl_xor(s,  o, 64);
        ss += __shfl_xor(ss, o, 64);
    }
    __shared__ float red[8];
    const int wid = t >> 6, lane = t & 63;
    if (lane == 0) { red[wid] = s; red[4 + wid] = ss; }
    __syncthreads();
    s  = red[0] + red[1] + red[2] + red[3];
    ss = red[4] + red[5] + red[6] + red[7];
    const float mean = s * (1.f / D_);
    const float var  = ss * (1.f / D_) - mean * mean;
    const float rstd = rsqrtf(var + 1e-5f);
    const float4 wv = reinterpret_cast<const float4*>(w)[t];
    const float4 bv = reinterpret_cast<const float4*>(b)[t];
    float4 o;
    o.x = (v.x - mean) * rstd * wv.x + bv.x;
    o.y = (v.y - mean) * rstd * wv.y + bv.y;
    o.z = (v.z - mean) * rstd * wv.z + bv.z;
    o.w = (v.w - mean) * rstd * wv.w + bv.w;
    if (OBF) {
        ushort4 o4;
        o4.x = f2bf_rne(o.x); o4.y = f2bf_rne(o.y);
        o4.z = f2bf_rne(o.z); o4.w = f2bf_rne(o.w);
        reinterpret_cast<ushort4*>((unsigned short*)y + (size_t)row * D_)[t] = o4;
    } else {
        reinterpret_cast<float4*>((float*)y + (size_t)row * D_)[t] = o;
    }
}

// ---------------- Weight transpose + cast: fp32 [K][N] -> bf16 [N][K] ------------------
__global__ __launch_bounds__(256) void wcast_kernel(
    const float* __restrict__ in, unsigned short* __restrict__ outT, int K, int N)
{
    __shared__ float t[64][65];
    const int n0 = blockIdx.x * 64, k0 = blockIdx.y * 64;
    const int tid = threadIdx.x;
    #pragma unroll
    for (int i = 0; i < 16; ++i) {
        const int idx = i * 256 + tid;
        const int kk = idx >> 6, nn = idx & 63;
        t[kk][nn] = in[(size_t)(k0 + kk) * N + n0 + nn];
    }
    __syncthreads();
    #pragma unroll
    for (int i = 0; i < 16; ++i) {
        const int idx = i * 256 + tid;
        const int nn = idx >> 6, kk = idx & 63;
        outT[(size_t)(n0 + nn) * K + k0 + kk] = f2bf_rne(t[kk][nn]);
    }
}

// ---------------- bf16 MFMA GEMM: C[M,N] = A[M,K] @ Bt[N,K]^T (+bias, epi) -------------
// 128x128 tile, BK=64, 4 waves (64x64 quadrant each, 32 MFMA per K-step).
// DOUBLE-BUFFERED: tile t+1's global_load_lds issued right after the barrier, BEFORE
// computing tile t -> load latency hides under ~700 cyc of ds_read+MFMA. The single
// __syncthreads per step drains batch t (issued one full compute-phase ago -> cheap)
// and guarantees buf^1's readers are done before it is overwritten. Source-side XOR
// swizzle (chunk ^= row&7 within the 128B row segment) + same involution on fragment
// reads -> 2-way LDS banks. Col-major XCD-chunked block swizzle -> B-panel L2-resident.
template<int EPI, bool OBF>  // EPI 0: +bias  1: +bias,relu  2: +bias,+residual
__global__ __launch_bounds__(256) void bgemm_kernel(
    const __bf16* __restrict__ A,   // [M][K] bf16
    const __bf16* __restrict__ Bt,  // [N][K] bf16 (pre-transposed)
    const float* __restrict__ bias, const float* __restrict__ res,
    void* __restrict__ Cv, int M, int N, int K)
{
    __shared__ __align__(16) __bf16 As[2][128 * 64];
    __shared__ __align__(16) __bf16 Bs[2][128 * 64];
    const int tid  = threadIdx.x;
    const int w    = tid >> 6, lane = tid & 63;
    const int wr   = w >> 1, wc = w & 1;

    // XCD-aware bijective remap (all grids %8==0); col-major tile decode so each
    // XCD's contiguous chunk shares a B column-panel (L2-resident).
    const int nwg  = gridDim.x;
    const int lin  = blockIdx.x;
    const int wg   = (lin & 7) * (nwg >> 3) + (lin >> 3);
    const int gridM = M >> 7;
    const int col0 = (wg / gridM) << 7;
    const int row0 = (wg % gridM) << 7;

    const int srow = lane >> 3;                 // staging row within 8-row chunk
    const int scol = ((lane & 7) ^ srow) << 3;  // swizzled source chunk (bf16 units)
    const int frow = lane & 15;                 // fragment row/col within 16x16
    const int l4   = lane >> 4;                 // fragment k-group
    const int r7   = frow & 7;                  // read-side swizzle key

    const __bf16* Abase = A  + (size_t)(row0 + srow) * K + scol;
    const __bf16* Bbase = Bt + (size_t)(col0 + srow) * K + scol;

    f32x4 acc[4][4] = {};
    const int nt = K >> 6;

#define STAGE_G(bufi, kt)                                                              \
    _Pragma("unroll")                                                                  \
    for (int it = 0; it < 4; ++it) {                                                   \
        const int arow = w * 32 + it * 8;                                              \
        __builtin_amdgcn_global_load_lds(                                              \
            (__attribute__((address_space(1))) void*)(Abase + (size_t)arow * K + (kt)),\
            (__attribute__((address_space(3))) void*)(&As[bufi][arow * 64]), 16, 0, 0);\
        __builtin_amdgcn_global_load_lds(                                              \
            (__attribute__((address_space(1))) void*)(Bbase + (size_t)arow * K + (kt)),\
            (__attribute__((address_space(3))) void*)(&Bs[bufi][arow * 64]), 16, 0, 0);\
    }

    STAGE_G(0, 0)
    int buf = 0;
    for (int t = 0; t < nt; ++t) {
        __syncthreads();          // drains batch t (issued one compute-phase ago)
        if (t + 1 < nt) {         // prefetch next tile; latency hides under MFMA below
            STAGE_G(buf ^ 1, (t + 1) << 6)
        }
        #pragma unroll
        for (int kk = 0; kk < 2; ++kk) {
            const int ch = ((kk * 4 + l4) ^ r7) * 8;
            bf16x8 af[4], bfr[4];
            #pragma unroll
            for (int i = 0; i < 4; ++i) {
                af[i]  = *(const bf16x8*)&As[buf][(wr * 64 + i * 16 + frow) * 64 + ch];
                bfr[i] = *(const bf16x8*)&Bs[buf][(wc * 64 + i * 16 + frow) * 64 + ch];
            }
            #pragma unroll
            for (int mi = 0; mi < 4; ++mi)
                #pragma unroll
                for (int ni = 0; ni < 4; ++ni)
                    acc[mi][ni] = __builtin_amdgcn_mfma_f32_16x16x32_bf16(
                        af[mi], bfr[ni], acc[mi][ni], 0, 0, 0);
        }
        buf ^= 1;
    }
#undef STAGE_G

    // epilogue: C/D layout col = lane&15, row = (lane>>4)*4 + reg
    float bz[4];
    #pragma unroll
    for (int ni = 0; ni < 4; ++ni) bz[ni] = bias[col0 + wc * 64 + ni * 16 + frow];
    #pragma unroll
    for (int mi = 0; mi < 4; ++mi) {
        #pragma unroll
        for (int j = 0; j < 4; ++j) {
            const int row = row0 + wr * 64 + mi * 16 + l4 * 4 + j;
            #pragma unroll
            for (int ni = 0; ni < 4; ++ni) {
                const int col = col0 + wc * 64 + ni * 16 + frow;
                float v = acc[mi][ni][j] + bz[ni];
                if (EPI == 1) v = fmaxf(v, 0.f);
                if (EPI == 2) v += res[(size_t)row * N + col];
                if (OBF) ((unsigned short*)Cv)[(size_t)row * N + col] = f2bf_rne(v);
                else     ((float*)Cv)[(size_t)row * N + col] = v;
            }
        }
    }
}

// ---------------- bf16 MFMA flash attention with ALiBi, causal -------------------------
// Grid: 1024 blocks = 32 qt x 32 (b,h); blockIdx = qtOrder*32 + bh keeps same-(b,h)
// on one XCD (bh mod 8 preserved) for K/V L2 locality; qt descending -> big blocks
// dispatch first, FIFO backfill balances causal skew. 4 blocks/CU (27.6 KB LDS).
__global__ __launch_bounds__(256) void attn_kernel(
    const __bf16* __restrict__ qkv, __bf16* __restrict__ ctx)
{
    const int bh   = blockIdx.x & 31;
    const int qt   = 31 - (blockIdx.x >> 5);
    const int b    = bh >> 4, h = bh & 15;
    const int tid  = threadIdx.x;
    const int wid  = tid >> 6, lane = tid & 63;
    const int l15  = lane & 15, l4 = lane >> 4;
    const float slope = exp2f(-(float)h);
    const size_t rowb = (size_t)b * S_;

    __shared__ __align__(16) __bf16 Ks[64 * 72];
    __shared__ __align__(16) __bf16 Vt[64 * 72];
    __shared__ __align__(16) __bf16 Ps[4 * 16 * 72];

    const int jr = tid >> 3;
    const int c  = tid & 7;
    const int c8 = c * 8;
    __bf16* psw = &Ps[wid * 16 * 72];
    const __bf16* base = qkv + rowb * 3072 + h * 64;

    const int i0 = qt << 6;

    bf16x8 qf[2];
    {
        const __bf16* qp = base + (size_t)(i0 + wid * 16 + l15) * 3072 + l4 * 8;
        qf[0] = *(const bf16x8*)(qp);
        qf[1] = *(const bf16x8*)(qp + 32);
    }

    float m[4], l[4];
    f32x4 acc[4];
    #pragma unroll
    for (int j = 0; j < 4; ++j) { m[j] = NEGINF; l[j] = 0.f; }
    #pragma unroll
    for (int ni = 0; ni < 4; ++ni) acc[ni] = (f32x4){0.f, 0.f, 0.f, 0.f};

    bf16x8 k0, k1, v0, v1;
    {   // prefetch tile 0
        const __bf16* kvp = base + (size_t)jr * 3072;
        k0 = *(const bf16x8*)(kvp + 1024 + c8);
        v0 = *(const bf16x8*)(kvp + 2048 + c8);
        k1 = *(const bf16x8*)(kvp + 32 * 3072 + 1024 + c8);
        v1 = *(const bf16x8*)(kvp + 32 * 3072 + 2048 + c8);
    }

    for (int kt = 0; kt <= qt; ++kt) {
        __syncthreads();
        *(bf16x8*)&Ks[jr * 72 + c8]        = k0;
        *(bf16x8*)&Ks[(jr + 32) * 72 + c8] = k1;
        const int sw0 = (((jr >> 3) ^ c) & 7) * 8 + (jr & 7);
        const int sw1 = ((((jr + 32) >> 3) ^ c) & 7) * 8 + (jr & 7);
        #pragma unroll
        for (int e = 0; e < 8; ++e) {
            Vt[(c8 + e) * 72 + sw0] = v0[e];
            Vt[(c8 + e) * 72 + sw1] = v1[e];
        }
        __syncthreads();

        if (kt < qt) {             // issue next tile's loads early (hide latency)
            const __bf16* kvp = base + (size_t)(((kt + 1) << 6) + jr) * 3072;
            k0 = *(const bf16x8*)(kvp + 1024 + c8);
            v0 = *(const bf16x8*)(kvp + 2048 + c8);
            k1 = *(const bf16x8*)(kvp + 32 * 3072 + 1024 + c8);
            v1 = *(const bf16x8*)(kvp + 32 * 3072 + 2048 + c8);
        }

        // ---- QK^T: S[16 q][64 k]
        f32x4 sf[4];
        #pragma unroll
        for (int ni = 0; ni < 4; ++ni) sf[ni] = (f32x4){0.f, 0.f, 0.f, 0.f};
        #pragma unroll
        for (int kd = 0; kd < 2; ++kd)
            #pragma unroll
            for (int ni = 0; ni < 4; ++ni) {
                const bf16x8 bf = *(const bf16x8*)&Ks[(ni * 16 + l15) * 72 + kd * 32 + l4 * 8];
                sf[ni] = __builtin_amdgcn_mfma_f32_16x16x32_bf16(qf[kd], bf, sf[ni], 0, 0, 0);
            }

        // ---- bias + mask (C layout: row = l4*4+j, col = ni*16+l15)
        float pv[4][4];
        const int j0 = kt << 6;
        if (kt == qt) {
            #pragma unroll
            for (int ni = 0; ni < 4; ++ni) {
                const int jcol = ni * 16 + l15;
                #pragma unroll
                for (int j = 0; j < 4; ++j) {
                    const int iloc = wid * 16 + l4 * 4 + j;
                    pv[ni][j] = (jcol <= iloc)
                        ? fmaf(slope, (float)(jcol - iloc), sf[ni][j] * 0.125f)
                        : NEGINF;
                }
            }
        } else {
            const float dbase = (float)(j0 - i0);
            #pragma unroll
            for (int ni = 0; ni < 4; ++ni) {
                const int jcol = ni * 16 + l15;
                #pragma unroll
                for (int j = 0; j < 4; ++j) {
                    const int iloc = wid * 16 + l4 * 4 + j;
                    pv[ni][j] = fmaf(slope, dbase + (float)(jcol - iloc), sf[ni][j] * 0.125f);
                }
            }
        }

        // ---- online softmax: rows live in 16-lane groups -> shfl_xor 1,2,4,8
        #pragma unroll
        for (int j = 0; j < 4; ++j) {
            float mx = fmaxf(fmaxf(pv[0][j], pv[1][j]), fmaxf(pv[2][j], pv[3][j]));
            mx = fmaxf(mx, __shfl_xor(mx, 1, 64));
            mx = fmaxf(mx, __shfl_xor(mx, 2, 64));
            mx = fmaxf(mx, __shfl_xor(mx, 4, 64));
            mx = fmaxf(mx, __shfl_xor(mx, 8, 64));
            const float mnew = fmaxf(m[j], mx);
            const float corr = __expf(m[j] - mnew);
            float s0 = 0.f;
            #pragma unroll
            for (int ni = 0; ni < 4; ++ni) {
                const float e = __expf(pv[ni][j] - mnew);
                pv[ni][j] = e;
                s0 += e;
            }
            s0 += __shfl_xor(s0, 1, 64);
            s0 += __shfl_xor(s0, 2, 64);
            s0 += __shfl_xor(s0, 4, 64);
            s0 += __shfl_xor(s0, 8, 64);
            l[j] = l[j] * corr + s0;
            m[j] = mnew;
            #pragma unroll
            for (int ni = 0; ni < 4; ++ni) acc[ni][j] *= corr;
        }

        // ---- stage P (per-wave; C-layout -> A-layout via LDS)
        #pragma unroll
        for (int ni = 0; ni < 4; ++ni)
            #pragma unroll
            for (int j = 0; j < 4; ++j)
                psw[(l4 * 4 + j) * 72 + ni * 16 + l15] = (__bf16)pv[ni][j];
        asm volatile("" ::: "memory");

        // ---- PV: ctx[16 q][64 d] += P @ V
        #pragma unroll
        for (int kk = 0; kk < 2; ++kk) {
            const bf16x8 pa = *(const bf16x8*)&psw[l15 * 72 + kk * 32 + l4 * 8];
            #pragma unroll
            for (int ni = 0; ni < 4; ++ni) {
                const int d = ni * 16 + l15;
                const int pc = ((kk * 4 + l4) ^ (d >> 3)) & 7;
                const bf16x8 bv = *(const bf16x8*)&Vt[d * 72 + pc * 8];
                acc[ni] = __builtin_amdgcn_mfma_f32_16x16x32_bf16(pa, bv, acc[ni], 0, 0, 0);
            }
        }
    }

    // ---- epilogue
    #pragma unroll
    for (int ni = 0; ni < 4; ++ni) {
        const int col = h * 64 + ni * 16 + l15;
        #pragma unroll
        for (int j = 0; j < 4; ++j) {
            const int row = i0 + wid * 16 + l4 * 4 + j;
            ctx[(rowb + row) * (size_t)D_ + col] = (__bf16)(acc[ni][j] / l[j]);
        }
    }
}

// ---------------- launch ----------------------------------------------------------------
extern "C" void kernel_launch(void* const* d_in, const int* in_sizes, int n_in,
                              void* d_out, int out_size, void* d_ws, size_t ws_size,
                              hipStream_t stream) {
    const float* src     = (const float*)d_in[0];
    const float* norm_w  = (const float*)d_in[1];
    const float* norm_b  = (const float*)d_in[2];
    const float* wqkv_w  = (const float*)d_in[3];
    const float* wqkv_b  = (const float*)d_in[4];
    const float* out_w   = (const float*)d_in[5];
    const float* out_b   = (const float*)d_in[6];
    const float* fnorm_w = (const float*)d_in[7];
    const float* fnorm_b = (const float*)d_in[8];
    const float* ff1_w   = (const float*)d_in[9];
    const float* ff1_b   = (const float*)d_in[10];
    const float* ff2_w   = (const float*)d_in[11];
    const float* ff2_b   = (const float*)d_in[12];
    float* out = (float*)d_out;

    const int M = 2 * S_;
    const size_t MB = 1u << 20;
    char* W = (char*)d_ws;
    unsigned short* wqkvT = (unsigned short*)(W);
    unsigned short* outT  = (unsigned short*)(W + 6  * MB);
    unsigned short* ff1T  = (unsigned short*)(W + 8  * MB);
    unsigned short* ff2T  = (unsigned short*)(W + 16 * MB);
    unsigned short* h1    = (unsigned short*)(W + 24 * MB);
    unsigned short* qkv   = (unsigned short*)(W + 32 * MB);
    unsigned short* ctx   = (unsigned short*)(W + 24 * MB);
    unsigned short* h2    = (unsigned short*)(W + 32 * MB);
    unsigned short* ffmid = (unsigned short*)(W + 40 * MB);
    float*          src2  = (float*)        (W + 80 * MB);

    wcast_kernel<<<dim3(3072/64, 1024/64), 256, 0, stream>>>(wqkv_w, wqkvT, 1024, 3072);
    wcast_kernel<<<dim3(1024/64, 1024/64), 256, 0, stream>>>(out_w,  outT,  1024, 1024);
    wcast_kernel<<<dim3(4096/64, 1024/64), 256, 0, stream>>>(ff1_w,  ff1T,  1024, 4096);
    wcast_kernel<<<dim3(1024/64, 4096/64), 256, 0, stream>>>(ff2_w,  ff2T,  4096, 1024);

    // 1) h1 = LN(src) -> bf16
    ln_kernel<true><<<M, 256, 0, stream>>>(src, norm_w, norm_b, h1);
    // 2) qkv = h1 @ wqkv_w + wqkv_b -> bf16  [4096 x 3072]  (768 blocks)
    bgemm_kernel<0, true><<<(3072/128) * (M/128), 256, 0, stream>>>(
        (const __bf16*)h1, (const __bf16*)wqkvT, wqkv_b, nullptr, qkv, M, 3072, 1024);
    // 3) ctx = flash-attn(q,k,v) -> bf16  (1024 blocks: 32 qt x 32 bh)
    attn_kernel<<<1024, 256, 0, stream>>>((const __bf16*)qkv, (__bf16*)ctx);
    // 4) src2 = src + ctx @ out_w + out_b  fp32  (256 blocks)
    bgemm_kernel<2, false><<<(1024/128) * (M/128), 256, 0, stream>>>(
        (const __bf16*)ctx, (const __bf16*)outT, out_b, src, src2, M, 1024, 1024);
    // 5) h2 = LN(src2) -> bf16
    ln_kernel<true><<<M, 256, 0, stream>>>(src2, fnorm_w, fnorm_b, h2);
    // 6) ffmid = relu(h2 @ ff1_w + ff1_b) -> bf16  [4096 x 4096]  (1024 blocks)
    bgemm_kernel<1, true><<<(4096/128) * (M/128), 256, 0, stream>>>(
        (const __bf16*)h2, (const __bf16*)ff1T, ff1_b, nullptr, ffmid, M, 4096, 1024);
    // 7) out = src2 + ffmid @ ff2_w + ff2_b  fp32  (256 blocks)
    bgemm_kernel<2, false><<<(1024/128) * (M/128), 256, 0, stream>>>(
        (const __bf16*)ffmid, (const __bf16*)ff2T, ff2_b, src2, out, M, 1024, 4096);
}

// Round 9
// 360.361 us; speedup vs baseline: 6.4719x; 1.0949x over previous
//
#include <hip/hip_runtime.h>
#include <math.h>

#define S_   2048
#define D_   1024
#define H_   16
#define DFF_ 4096

#define NEGINF (-__builtin_huge_valf())

typedef __bf16 bf16x8 __attribute__((ext_vector_type(8)));
typedef __bf16 bf16x4 __attribute__((ext_vector_type(4)));
typedef float  f32x4  __attribute__((ext_vector_type(4)));

static __device__ __forceinline__ unsigned short f2bf_rne(float f) {
    unsigned int u = __float_as_uint(f);
    u = (u + 0x7fffu + ((u >> 16) & 1u)) >> 16;
    return (unsigned short)u;
}

// ---------------- LayerNorm: one row (1024 floats) per 256-thread block ----------------
template<bool OBF>
__global__ __launch_bounds__(256) void ln_kernel(
    const float* __restrict__ x, const float* __restrict__ w,
    const float* __restrict__ b, void* __restrict__ y)
{
    const int row = blockIdx.x;
    const int t = threadIdx.x;
    const float4 v = reinterpret_cast<const float4*>(x + (size_t)row * D_)[t];
    float s  = v.x + v.y + v.z + v.w;
    float ss = v.x*v.x + v.y*v.y + v.z*v.z + v.w*v.w;
    #pragma unroll
    for (int o = 32; o; o >>= 1) {
        s  += __shfl_xor(s,  o, 64);
        ss += __shfl_xor(ss, o, 64);
    }
    __shared__ float red[8];
    const int wid = t >> 6, lane = t & 63;
    if (lane == 0) { red[wid] = s; red[4 + wid] = ss; }
    __syncthreads();
    s  = red[0] + red[1] + red[2] + red[3];
    ss = red[4] + red[5] + red[6] + red[7];
    const float mean = s * (1.f / D_);
    const float var  = ss * (1.f / D_) - mean * mean;
    const float rstd = rsqrtf(var + 1e-5f);
    const float4 wv = reinterpret_cast<const float4*>(w)[t];
    const float4 bv = reinterpret_cast<const float4*>(b)[t];
    float4 o;
    o.x = (v.x - mean) * rstd * wv.x + bv.x;
    o.y = (v.y - mean) * rstd * wv.y + bv.y;
    o.z = (v.z - mean) * rstd * wv.z + bv.z;
    o.w = (v.w - mean) * rstd * wv.w + bv.w;
    if (OBF) {
        ushort4 o4;
        o4.x = f2bf_rne(o.x); o4.y = f2bf_rne(o.y);
        o4.z = f2bf_rne(o.z); o4.w = f2bf_rne(o.w);
        reinterpret_cast<ushort4*>((unsigned short*)y + (size_t)row * D_)[t] = o4;
    } else {
        reinterpret_cast<float4*>((float*)y + (size_t)row * D_)[t] = o;
    }
}

// ---------------- Weight transpose + cast: fp32 [K][N] -> bf16 [N][K] ------------------
__global__ __launch_bounds__(256) void wcast_kernel(
    const float* __restrict__ in, unsigned short* __restrict__ outT, int K, int N)
{
    __shared__ float t[64][65];
    const int n0 = blockIdx.x * 64, k0 = blockIdx.y * 64;
    const int tid = threadIdx.x;
    #pragma unroll
    for (int i = 0; i < 16; ++i) {
        const int idx = i * 256 + tid;
        const int kk = idx >> 6, nn = idx & 63;
        t[kk][nn] = in[(size_t)(k0 + kk) * N + n0 + nn];
    }
    __syncthreads();
    #pragma unroll
    for (int i = 0; i < 16; ++i) {
        const int idx = i * 256 + tid;
        const int nn = idx >> 6, kk = idx & 63;
        outT[(size_t)(n0 + nn) * K + k0 + kk] = f2bf_rne(t[kk][nn]);
    }
}

// ---------------- bf16 MFMA GEMM: C[M,N] = A[M,K] @ Bt[N,K]^T (+bias, epi) -------------
// 128x128 tile, BK=64, double-buffered (prefetch t+1 before computing t); source-side
// XOR swizzle + same involution on fragment reads; col-major XCD-chunked block swizzle.
template<int EPI, bool OBF>  // EPI 0: +bias  1: +bias,relu  2: +bias,+residual
__global__ __launch_bounds__(256) void bgemm_kernel(
    const __bf16* __restrict__ A,   // [M][K] bf16
    const __bf16* __restrict__ Bt,  // [N][K] bf16 (pre-transposed)
    const float* __restrict__ bias, const float* __restrict__ res,
    void* __restrict__ Cv, int M, int N, int K)
{
    __shared__ __align__(16) __bf16 As[2][128 * 64];
    __shared__ __align__(16) __bf16 Bs[2][128 * 64];
    const int tid  = threadIdx.x;
    const int w    = tid >> 6, lane = tid & 63;
    const int wr   = w >> 1, wc = w & 1;

    const int nwg  = gridDim.x;
    const int lin  = blockIdx.x;
    const int wg   = (lin & 7) * (nwg >> 3) + (lin >> 3);
    const int gridM = M >> 7;
    const int col0 = (wg / gridM) << 7;
    const int row0 = (wg % gridM) << 7;

    const int srow = lane >> 3;
    const int scol = ((lane & 7) ^ srow) << 3;
    const int frow = lane & 15;
    const int l4   = lane >> 4;
    const int r7   = frow & 7;

    const __bf16* Abase = A  + (size_t)(row0 + srow) * K + scol;
    const __bf16* Bbase = Bt + (size_t)(col0 + srow) * K + scol;

    f32x4 acc[4][4] = {};
    const int nt = K >> 6;

#define STAGE_G(bufi, kt)                                                              \
    _Pragma("unroll")                                                                  \
    for (int it = 0; it < 4; ++it) {                                                   \
        const int arow = w * 32 + it * 8;                                              \
        __builtin_amdgcn_global_load_lds(                                              \
            (__attribute__((address_space(1))) void*)(Abase + (size_t)arow * K + (kt)),\
            (__attribute__((address_space(3))) void*)(&As[bufi][arow * 64]), 16, 0, 0);\
        __builtin_amdgcn_global_load_lds(                                              \
            (__attribute__((address_space(1))) void*)(Bbase + (size_t)arow * K + (kt)),\
            (__attribute__((address_space(3))) void*)(&Bs[bufi][arow * 64]), 16, 0, 0);\
    }

    STAGE_G(0, 0)
    int buf = 0;
    for (int t = 0; t < nt; ++t) {
        __syncthreads();
        if (t + 1 < nt) {
            STAGE_G(buf ^ 1, (t + 1) << 6)
        }
        #pragma unroll
        for (int kk = 0; kk < 2; ++kk) {
            const int ch = ((kk * 4 + l4) ^ r7) * 8;
            bf16x8 af[4], bfr[4];
            #pragma unroll
            for (int i = 0; i < 4; ++i) {
                af[i]  = *(const bf16x8*)&As[buf][(wr * 64 + i * 16 + frow) * 64 + ch];
                bfr[i] = *(const bf16x8*)&Bs[buf][(wc * 64 + i * 16 + frow) * 64 + ch];
            }
            #pragma unroll
            for (int mi = 0; mi < 4; ++mi)
                #pragma unroll
                for (int ni = 0; ni < 4; ++ni)
                    acc[mi][ni] = __builtin_amdgcn_mfma_f32_16x16x32_bf16(
                        af[mi], bfr[ni], acc[mi][ni], 0, 0, 0);
        }
        buf ^= 1;
    }
#undef STAGE_G

    float bz[4];
    #pragma unroll
    for (int ni = 0; ni < 4; ++ni) bz[ni] = bias[col0 + wc * 64 + ni * 16 + frow];
    #pragma unroll
    for (int mi = 0; mi < 4; ++mi) {
        #pragma unroll
        for (int j = 0; j < 4; ++j) {
            const int row = row0 + wr * 64 + mi * 16 + l4 * 4 + j;
            #pragma unroll
            for (int ni = 0; ni < 4; ++ni) {
                const int col = col0 + wc * 64 + ni * 16 + frow;
                float v = acc[mi][ni][j] + bz[ni];
                if (EPI == 1) v = fmaxf(v, 0.f);
                if (EPI == 2) v += res[(size_t)row * N + col];
                if (OBF) ((unsigned short*)Cv)[(size_t)row * N + col] = f2bf_rne(v);
                else     ((float*)Cv)[(size_t)row * N + col] = v;
            }
        }
    }
}

// ---------------- bf16 MFMA flash attention with ALiBi, causal -------------------------
// Swapped QK^T (mfma(K,Q) -> S^T): each lane owns ONE query (l15), 16 score values.
// No max-tracking (scores bounded: |q.k|*0.125 <= ~12, bias <= 0 -> exp2 args safe in
// fp32) and DEFERRED row-sum (per-lane scalar partial, one 2-shfl reduce at the end):
// zero per-step shuffles, no acc rescale. Q pre-scaled by 0.125*log2e; slope and (k-i)
// folded into per-lane constants. P staged [query][key] -> 4x ds_write_b64 per step.
__global__ __launch_bounds__(256) void attn_kernel(
    const __bf16* __restrict__ qkv, __bf16* __restrict__ ctx)
{
    const int bh   = blockIdx.x & 31;
    const int qt   = 31 - (blockIdx.x >> 5);
    const int b    = bh >> 4, h = bh & 15;
    const int tid  = threadIdx.x;
    const int wid  = tid >> 6, lane = tid & 63;
    const int l15  = lane & 15, l4 = lane >> 4;
    const float slope2 = exp2f(-(float)h) * 1.44269504f;   // slope * log2(e)
    const size_t rowb = (size_t)b * S_;

    __shared__ __align__(16) __bf16 Ks[64 * 72];
    __shared__ __align__(16) __bf16 Vt[64 * 72];
    __shared__ __align__(16) __bf16 Ps[4 * 16 * 72];

    const int jr = tid >> 3;
    const int c  = tid & 7;
    const int c8 = c * 8;
    __bf16* psw = &Ps[wid * 16 * 72];
    const __bf16* base = qkv + rowb * 3072 + h * 64;

    const int i0 = qt << 6;

    // Q load + prescale by 0.125*log2(e), repack bf16 (once per block)
    bf16x8 qf[2];
    {
        const float QSC = 0.125f * 1.44269504f;
        const __bf16* qp = base + (size_t)(i0 + wid * 16 + l15) * 3072 + l4 * 8;
        bf16x8 r0 = *(const bf16x8*)(qp);
        bf16x8 r1 = *(const bf16x8*)(qp + 32);
        #pragma unroll
        for (int e = 0; e < 8; ++e) {
            qf[0][e] = (__bf16)((float)r0[e] * QSC);
            qf[1][e] = (__bf16)((float)r1[e] * QSC);
        }
    }

    // per-lane ALiBi constants: cb[ni][j] = slope2 * ((ni*16+l4*4+j) - (wid*16+l15));
    // on the diagonal tile (j0==i0), mask condition (key>query) is simply cb > 0.
    float cb[4][4];
    #pragma unroll
    for (int ni = 0; ni < 4; ++ni)
        #pragma unroll
        for (int j = 0; j < 4; ++j)
            cb[ni][j] = slope2 * (float)(ni * 16 + l4 * 4 + j - wid * 16 - l15);

    float lsum = 0.f;
    f32x4 acc[4];
    #pragma unroll
    for (int ni = 0; ni < 4; ++ni) acc[ni] = (f32x4){0.f, 0.f, 0.f, 0.f};

    bf16x8 k0, k1, v0, v1;
    {   // prefetch tile 0
        const __bf16* kvp = base + (size_t)jr * 3072;
        k0 = *(const bf16x8*)(kvp + 1024 + c8);
        v0 = *(const bf16x8*)(kvp + 2048 + c8);
        k1 = *(const bf16x8*)(kvp + 32 * 3072 + 1024 + c8);
        v1 = *(const bf16x8*)(kvp + 32 * 3072 + 2048 + c8);
    }

    for (int kt = 0; kt <= qt; ++kt) {
        __syncthreads();
        *(bf16x8*)&Ks[jr * 72 + c8]        = k0;
        *(bf16x8*)&Ks[(jr + 32) * 72 + c8] = k1;
        const int sw0 = (((jr >> 3) ^ c) & 7) * 8 + (jr & 7);
        const int sw1 = ((((jr + 32) >> 3) ^ c) & 7) * 8 + (jr & 7);
        #pragma unroll
        for (int e = 0; e < 8; ++e) {
            Vt[(c8 + e) * 72 + sw0] = v0[e];
            Vt[(c8 + e) * 72 + sw1] = v1[e];
        }
        __syncthreads();

        if (kt < qt) {             // issue next tile's loads early (hide latency)
            const __bf16* kvp = base + (size_t)(((kt + 1) << 6) + jr) * 3072;
            k0 = *(const bf16x8*)(kvp + 1024 + c8);
            v0 = *(const bf16x8*)(kvp + 2048 + c8);
            k1 = *(const bf16x8*)(kvp + 32 * 3072 + 1024 + c8);
            v1 = *(const bf16x8*)(kvp + 32 * 3072 + 2048 + c8);
        }

        // ---- QK^T swapped: sf[ni] = S^T[key tile ni][query]; lane: key=l4*4+j, query=l15
        f32x4 sf[4];
        #pragma unroll
        for (int ni = 0; ni < 4; ++ni) sf[ni] = (f32x4){0.f, 0.f, 0.f, 0.f};
        #pragma unroll
        for (int kd = 0; kd < 2; ++kd)
            #pragma unroll
            for (int ni = 0; ni < 4; ++ni) {
                const bf16x8 kf = *(const bf16x8*)&Ks[(ni * 16 + l15) * 72 + kd * 32 + l4 * 8];
                sf[ni] = __builtin_amdgcn_mfma_f32_16x16x32_bf16(kf, qf[kd], sf[ni], 0, 0, 0);
            }

        // ---- softmax-lite: P = exp2(sf + bias2), no max-sub, per-lane deferred sum
        float p[4][4];
        if (kt == qt) {
            #pragma unroll
            for (int ni = 0; ni < 4; ++ni)
                #pragma unroll
                for (int j = 0; j < 4; ++j) {
                    const float e = (cb[ni][j] > 0.f)
                        ? 0.f
                        : __builtin_amdgcn_exp2f(sf[ni][j] + cb[ni][j]);
                    p[ni][j] = e;
                    lsum += e;
                }
        } else {
            const float dstep = slope2 * (float)((kt << 6) - i0);
            #pragma unroll
            for (int ni = 0; ni < 4; ++ni)
                #pragma unroll
                for (int j = 0; j < 4; ++j) {
                    const float e = __builtin_amdgcn_exp2f(sf[ni][j] + (cb[ni][j] + dstep));
                    p[ni][j] = e;
                    lsum += e;
                }
        }

        // ---- stage P [query][key]: 4x b64 writes (4 contiguous keys each)
        #pragma unroll
        for (int ni = 0; ni < 4; ++ni) {
            bf16x4 pk;
            pk[0] = (__bf16)p[ni][0]; pk[1] = (__bf16)p[ni][1];
            pk[2] = (__bf16)p[ni][2]; pk[3] = (__bf16)p[ni][3];
            *(bf16x4*)&psw[l15 * 72 + ni * 16 + l4 * 4] = pk;
        }
        asm volatile("" ::: "memory");

        // ---- PV: acc[query][d] += P @ V   (A=P[query][key], B=Vt[d][key])
        #pragma unroll
        for (int kk = 0; kk < 2; ++kk) {
            const bf16x8 pa = *(const bf16x8*)&psw[l15 * 72 + kk * 32 + l4 * 8];
            #pragma unroll
            for (int ni = 0; ni < 4; ++ni) {
                const int d = ni * 16 + l15;
                const int pc = ((kk * 4 + l4) ^ (d >> 3)) & 7;
                const bf16x8 bv = *(const bf16x8*)&Vt[d * 72 + pc * 8];
                acc[ni] = __builtin_amdgcn_mfma_f32_16x16x32_bf16(pa, bv, acc[ni], 0, 0, 0);
            }
        }
    }

    // ---- final l reduction: combine the 4 key-partitions of each query, broadcast
    lsum += __shfl_xor(lsum, 16, 64);
    lsum += __shfl_xor(lsum, 32, 64);
    float linv[4];
    #pragma unroll
    for (int j = 0; j < 4; ++j)
        linv[j] = 1.f / __shfl(lsum, l4 * 4 + j, 64);

    // ---- epilogue (acc layout unchanged: row=query=l4*4+j, col=d=ni*16+l15)
    #pragma unroll
    for (int ni = 0; ni < 4; ++ni) {
        const int col = h * 64 + ni * 16 + l15;
        #pragma unroll
        for (int j = 0; j < 4; ++j) {
            const int row = i0 + wid * 16 + l4 * 4 + j;
            ctx[(rowb + row) * (size_t)D_ + col] = (__bf16)(acc[ni][j] * linv[j]);
        }
    }
}

// ---------------- launch ----------------------------------------------------------------
extern "C" void kernel_launch(void* const* d_in, const int* in_sizes, int n_in,
                              void* d_out, int out_size, void* d_ws, size_t ws_size,
                              hipStream_t stream) {
    const float* src     = (const float*)d_in[0];
    const float* norm_w  = (const float*)d_in[1];
    const float* norm_b  = (const float*)d_in[2];
    const float* wqkv_w  = (const float*)d_in[3];
    const float* wqkv_b  = (const float*)d_in[4];
    const float* out_w   = (const float*)d_in[5];
    const float* out_b   = (const float*)d_in[6];
    const float* fnorm_w = (const float*)d_in[7];
    const float* fnorm_b = (const float*)d_in[8];
    const float* ff1_w   = (const float*)d_in[9];
    const float* ff1_b   = (const float*)d_in[10];
    const float* ff2_w   = (const float*)d_in[11];
    const float* ff2_b   = (const float*)d_in[12];
    float* out = (float*)d_out;

    const int M = 2 * S_;
    const size_t MB = 1u << 20;
    char* W = (char*)d_ws;
    unsigned short* wqkvT = (unsigned short*)(W);
    unsigned short* outT  = (unsigned short*)(W + 6  * MB);
    unsigned short* ff1T  = (unsigned short*)(W + 8  * MB);
    unsigned short* ff2T  = (unsigned short*)(W + 16 * MB);
    unsigned short* h1    = (unsigned short*)(W + 24 * MB);
    unsigned short* qkv   = (unsigned short*)(W + 32 * MB);
    unsigned short* ctx   = (unsigned short*)(W + 24 * MB);
    unsigned short* h2    = (unsigned short*)(W + 32 * MB);
    unsigned short* ffmid = (unsigned short*)(W + 40 * MB);
    float*          src2  = (float*)        (W + 80 * MB);

    wcast_kernel<<<dim3(3072/64, 1024/64), 256, 0, stream>>>(wqkv_w, wqkvT, 1024, 3072);
    wcast_kernel<<<dim3(1024/64, 1024/64), 256, 0, stream>>>(out_w,  outT,  1024, 1024);
    wcast_kernel<<<dim3(4096/64, 1024/64), 256, 0, stream>>>(ff1_w,  ff1T,  1024, 4096);
    wcast_kernel<<<dim3(1024/64, 4096/64), 256, 0, stream>>>(ff2_w,  ff2T,  4096, 1024);

    // 1) h1 = LN(src) -> bf16
    ln_kernel<true><<<M, 256, 0, stream>>>(src, norm_w, norm_b, h1);
    // 2) qkv = h1 @ wqkv_w + wqkv_b -> bf16  [4096 x 3072]
    bgemm_kernel<0, true><<<(3072/128) * (M/128), 256, 0, stream>>>(
        (const __bf16*)h1, (const __bf16*)wqkvT, wqkv_b, nullptr, qkv, M, 3072, 1024);
    // 3) ctx = flash-attn(q,k,v) -> bf16  (1024 blocks: 32 qt x 32 bh)
    attn_kernel<<<1024, 256, 0, stream>>>((const __bf16*)qkv, (__bf16*)ctx);
    // 4) src2 = src + ctx @ out_w + out_b  fp32
    bgemm_kernel<2, false><<<(1024/128) * (M/128), 256, 0, stream>>>(
        (const __bf16*)ctx, (const __bf16*)outT, out_b, src, src2, M, 1024, 1024);
    // 5) h2 = LN(src2) -> bf16
    ln_kernel<true><<<M, 256, 0, stream>>>(src2, fnorm_w, fnorm_b, h2);
    // 6) ffmid = relu(h2 @ ff1_w + ff1_b) -> bf16  [4096 x 4096]
    bgemm_kernel<1, true><<<(4096/128) * (M/128), 256, 0, stream>>>(
        (const __bf16*)h2, (const __bf16*)ff1T, ff1_b, nullptr, ffmid, M, 4096, 1024);
    // 7) out = src2 + ffmid @ ff2_w + ff2_b  fp32
    bgemm_kernel<2, false><<<(1024/128) * (M/128), 256, 0, stream>>>(
        (const __bf16*)ffmid, (const __bf16*)ff2T, ff2_b, src2, out, M, 1024, 4096);
}

// Round 10
// 344.493 us; speedup vs baseline: 6.7700x; 1.0461x over previous
//
#include <hip/hip_runtime.h>
#include <math.h>

#define S_   2048
#define D_   1024
#define H_   16
#define DFF_ 4096

#define NEGINF (-__builtin_huge_valf())

typedef __bf16 bf16x8 __attribute__((ext_vector_type(8)));
typedef __bf16 bf16x4 __attribute__((ext_vector_type(4)));
typedef float  f32x4  __attribute__((ext_vector_type(4)));

static __device__ __forceinline__ unsigned short f2bf_rne(float f) {
    unsigned int u = __float_as_uint(f);
    u = (u + 0x7fffu + ((u >> 16) & 1u)) >> 16;
    return (unsigned short)u;
}

// ---------------- LayerNorm: one row (1024 floats) per 256-thread block ----------------
template<bool OBF>
__global__ __launch_bounds__(256) void ln_kernel(
    const float* __restrict__ x, const float* __restrict__ w,
    const float* __restrict__ b, void* __restrict__ y)
{
    const int row = blockIdx.x;
    const int t = threadIdx.x;
    const float4 v = reinterpret_cast<const float4*>(x + (size_t)row * D_)[t];
    float s  = v.x + v.y + v.z + v.w;
    float ss = v.x*v.x + v.y*v.y + v.z*v.z + v.w*v.w;
    #pragma unroll
    for (int o = 32; o; o >>= 1) {
        s  += __shfl_xor(s,  o, 64);
        ss += __shfl_xor(ss, o, 64);
    }
    __shared__ float red[8];
    const int wid = t >> 6, lane = t & 63;
    if (lane == 0) { red[wid] = s; red[4 + wid] = ss; }
    __syncthreads();
    s  = red[0] + red[1] + red[2] + red[3];
    ss = red[4] + red[5] + red[6] + red[7];
    const float mean = s * (1.f / D_);
    const float var  = ss * (1.f / D_) - mean * mean;
    const float rstd = rsqrtf(var + 1e-5f);
    const float4 wv = reinterpret_cast<const float4*>(w)[t];
    const float4 bv = reinterpret_cast<const float4*>(b)[t];
    float4 o;
    o.x = (v.x - mean) * rstd * wv.x + bv.x;
    o.y = (v.y - mean) * rstd * wv.y + bv.y;
    o.z = (v.z - mean) * rstd * wv.z + bv.z;
    o.w = (v.w - mean) * rstd * wv.w + bv.w;
    if (OBF) {
        ushort4 o4;
        o4.x = f2bf_rne(o.x); o4.y = f2bf_rne(o.y);
        o4.z = f2bf_rne(o.z); o4.w = f2bf_rne(o.w);
        reinterpret_cast<ushort4*>((unsigned short*)y + (size_t)row * D_)[t] = o4;
    } else {
        reinterpret_cast<float4*>((float*)y + (size_t)row * D_)[t] = o;
    }
}

// ---------------- Weight transpose + cast: fp32 [K][N] -> bf16 [N][K] ------------------
__global__ __launch_bounds__(256) void wcast_kernel(
    const float* __restrict__ in, unsigned short* __restrict__ outT, int K, int N)
{
    __shared__ float t[64][65];
    const int n0 = blockIdx.x * 64, k0 = blockIdx.y * 64;
    const int tid = threadIdx.x;
    #pragma unroll
    for (int i = 0; i < 16; ++i) {
        const int idx = i * 256 + tid;
        const int kk = idx >> 6, nn = idx & 63;
        t[kk][nn] = in[(size_t)(k0 + kk) * N + n0 + nn];
    }
    __syncthreads();
    #pragma unroll
    for (int i = 0; i < 16; ++i) {
        const int idx = i * 256 + tid;
        const int nn = idx >> 6, kk = idx & 63;
        outT[(size_t)(n0 + nn) * K + k0 + kk] = f2bf_rne(t[kk][nn]);
    }
}

// ---------------- bf16 MFMA GEMM: C[M,N] = A[M,K] @ Bt[N,K]^T (+bias, epi) -------------
// 128xBN tile (BN=128: 4 waves in 2x2, 64x64 each; BN=64: 4 waves stacked, 32x64 each),
// BK=64, double-buffered (prefetch t+1 before computing t). Source-side XOR swizzle +
// same involution on fragment reads -> 0 bank conflicts. Col-major XCD-chunked block
// swizzle. BN=64 doubles the grid for N=1024 shapes -> 2 blocks/CU (cross-block overlap
// hides the per-step barrier/vmcnt drain that capped 1-block/CU shapes at 17% MfmaUtil).
template<int EPI, bool OBF, int BN>  // EPI 0: +bias  1: +bias,relu  2: +bias,+residual
__global__ __launch_bounds__(256) void bgemm_kernel(
    const __bf16* __restrict__ A,   // [M][K] bf16
    const __bf16* __restrict__ Bt,  // [N][K] bf16 (pre-transposed)
    const float* __restrict__ bias, const float* __restrict__ res,
    void* __restrict__ Cv, int M, int N, int K)
{
    constexpr int B_IT = BN / 32;                 // B staging instrs per wave
    constexpr int MI   = (BN == 128) ? 4 : 2;     // 16-row frags per wave
    __shared__ __align__(16) __bf16 As[2][128 * 64];
    __shared__ __align__(16) __bf16 Bs[2][BN * 64];
    const int tid  = threadIdx.x;
    const int w    = tid >> 6, lane = tid & 63;
    const int wrow0 = (BN == 128) ? (w >> 1) * 64 : w * 32;
    const int wcol0 = (BN == 128) ? (w & 1) * 64 : 0;

    const int nwg  = gridDim.x;
    const int lin  = blockIdx.x;
    const int wg   = (lin & 7) * (nwg >> 3) + (lin >> 3);
    const int gridM = M >> 7;
    const int col0 = (wg / gridM) * BN;
    const int row0 = (wg % gridM) << 7;

    const int srow = lane >> 3;
    const int scol = ((lane & 7) ^ srow) << 3;
    const int frow = lane & 15;
    const int l4   = lane >> 4;
    const int r7   = frow & 7;

    const __bf16* Abase = A  + (size_t)(row0 + srow) * K + scol;
    const __bf16* Bbase = Bt + (size_t)(col0 + srow) * K + scol;

    f32x4 acc[MI][4] = {};
    const int nt = K >> 6;

#define STAGE_G(bufi, kt)                                                              \
    _Pragma("unroll")                                                                  \
    for (int it = 0; it < 4; ++it) {                                                   \
        const int arow = w * 32 + it * 8;                                              \
        __builtin_amdgcn_global_load_lds(                                              \
            (__attribute__((address_space(1))) void*)(Abase + (size_t)arow * K + (kt)),\
            (__attribute__((address_space(3))) void*)(&As[bufi][arow * 64]), 16, 0, 0);\
    }                                                                                  \
    _Pragma("unroll")                                                                  \
    for (int it = 0; it < B_IT; ++it) {                                                \
        const int brow = w * (BN / 4) + it * 8;                                        \
        __builtin_amdgcn_global_load_lds(                                              \
            (__attribute__((address_space(1))) void*)(Bbase + (size_t)brow * K + (kt)),\
            (__attribute__((address_space(3))) void*)(&Bs[bufi][brow * 64]), 16, 0, 0);\
    }

    STAGE_G(0, 0)
    int buf = 0;
    for (int t = 0; t < nt; ++t) {
        __syncthreads();          // drains batch t (issued one compute-phase ago)
        if (t + 1 < nt) {         // prefetch next tile; latency hides under MFMA below
            STAGE_G(buf ^ 1, (t + 1) << 6)
        }
        #pragma unroll
        for (int kk = 0; kk < 2; ++kk) {
            const int ch = ((kk * 4 + l4) ^ r7) * 8;
            bf16x8 af[MI], bfr[4];
            #pragma unroll
            for (int i = 0; i < MI; ++i)
                af[i] = *(const bf16x8*)&As[buf][(wrow0 + i * 16 + frow) * 64 + ch];
            #pragma unroll
            for (int i = 0; i < 4; ++i)
                bfr[i] = *(const bf16x8*)&Bs[buf][(wcol0 + i * 16 + frow) * 64 + ch];
            #pragma unroll
            for (int mi = 0; mi < MI; ++mi)
                #pragma unroll
                for (int ni = 0; ni < 4; ++ni)
                    acc[mi][ni] = __builtin_amdgcn_mfma_f32_16x16x32_bf16(
                        af[mi], bfr[ni], acc[mi][ni], 0, 0, 0);
        }
        buf ^= 1;
    }
#undef STAGE_G

    float bz[4];
    #pragma unroll
    for (int ni = 0; ni < 4; ++ni) bz[ni] = bias[col0 + wcol0 + ni * 16 + frow];
    #pragma unroll
    for (int mi = 0; mi < MI; ++mi) {
        #pragma unroll
        for (int j = 0; j < 4; ++j) {
            const int row = row0 + wrow0 + mi * 16 + l4 * 4 + j;
            #pragma unroll
            for (int ni = 0; ni < 4; ++ni) {
                const int col = col0 + wcol0 + ni * 16 + frow;
                float v = acc[mi][ni][j] + bz[ni];
                if (EPI == 1) v = fmaxf(v, 0.f);
                if (EPI == 2) v += res[(size_t)row * N + col];
                if (OBF) ((unsigned short*)Cv)[(size_t)row * N + col] = f2bf_rne(v);
                else     ((float*)Cv)[(size_t)row * N + col] = v;
            }
        }
    }
}

// ---------------- bf16 MFMA flash attention with ALiBi, causal -------------------------
// Swapped QK^T (mfma(K,Q) -> S^T): each lane owns ONE query (l15), 16 score values.
// No max-tracking (scores bounded) + DEFERRED row-sum: zero per-step shuffles.
__global__ __launch_bounds__(256) void attn_kernel(
    const __bf16* __restrict__ qkv, __bf16* __restrict__ ctx)
{
    const int bh   = blockIdx.x & 31;
    const int qt   = 31 - (blockIdx.x >> 5);
    const int b    = bh >> 4, h = bh & 15;
    const int tid  = threadIdx.x;
    const int wid  = tid >> 6, lane = tid & 63;
    const int l15  = lane & 15, l4 = lane >> 4;
    const float slope2 = exp2f(-(float)h) * 1.44269504f;   // slope * log2(e)
    const size_t rowb = (size_t)b * S_;

    __shared__ __align__(16) __bf16 Ks[64 * 72];
    __shared__ __align__(16) __bf16 Vt[64 * 72];
    __shared__ __align__(16) __bf16 Ps[4 * 16 * 72];

    const int jr = tid >> 3;
    const int c  = tid & 7;
    const int c8 = c * 8;
    __bf16* psw = &Ps[wid * 16 * 72];
    const __bf16* base = qkv + rowb * 3072 + h * 64;

    const int i0 = qt << 6;

    bf16x8 qf[2];
    {
        const float QSC = 0.125f * 1.44269504f;
        const __bf16* qp = base + (size_t)(i0 + wid * 16 + l15) * 3072 + l4 * 8;
        bf16x8 r0 = *(const bf16x8*)(qp);
        bf16x8 r1 = *(const bf16x8*)(qp + 32);
        #pragma unroll
        for (int e = 0; e < 8; ++e) {
            qf[0][e] = (__bf16)((float)r0[e] * QSC);
            qf[1][e] = (__bf16)((float)r1[e] * QSC);
        }
    }

    float cb[4][4];
    #pragma unroll
    for (int ni = 0; ni < 4; ++ni)
        #pragma unroll
        for (int j = 0; j < 4; ++j)
            cb[ni][j] = slope2 * (float)(ni * 16 + l4 * 4 + j - wid * 16 - l15);

    float lsum = 0.f;
    f32x4 acc[4];
    #pragma unroll
    for (int ni = 0; ni < 4; ++ni) acc[ni] = (f32x4){0.f, 0.f, 0.f, 0.f};

    bf16x8 k0, k1, v0, v1;
    {   // prefetch tile 0
        const __bf16* kvp = base + (size_t)jr * 3072;
        k0 = *(const bf16x8*)(kvp + 1024 + c8);
        v0 = *(const bf16x8*)(kvp + 2048 + c8);
        k1 = *(const bf16x8*)(kvp + 32 * 3072 + 1024 + c8);
        v1 = *(const bf16x8*)(kvp + 32 * 3072 + 2048 + c8);
    }

    for (int kt = 0; kt <= qt; ++kt) {
        __syncthreads();
        *(bf16x8*)&Ks[jr * 72 + c8]        = k0;
        *(bf16x8*)&Ks[(jr + 32) * 72 + c8] = k1;
        const int sw0 = (((jr >> 3) ^ c) & 7) * 8 + (jr & 7);
        const int sw1 = ((((jr + 32) >> 3) ^ c) & 7) * 8 + (jr & 7);
        #pragma unroll
        for (int e = 0; e < 8; ++e) {
            Vt[(c8 + e) * 72 + sw0] = v0[e];
            Vt[(c8 + e) * 72 + sw1] = v1[e];
        }
        __syncthreads();

        if (kt < qt) {             // issue next tile's loads early (hide latency)
            const __bf16* kvp = base + (size_t)(((kt + 1) << 6) + jr) * 3072;
            k0 = *(const bf16x8*)(kvp + 1024 + c8);
            v0 = *(const bf16x8*)(kvp + 2048 + c8);
            k1 = *(const bf16x8*)(kvp + 32 * 3072 + 1024 + c8);
            v1 = *(const bf16x8*)(kvp + 32 * 3072 + 2048 + c8);
        }

        // ---- QK^T swapped: sf[ni] = S^T[key tile ni][query]; lane: key=l4*4+j, query=l15
        f32x4 sf[4];
        #pragma unroll
        for (int ni = 0; ni < 4; ++ni) sf[ni] = (f32x4){0.f, 0.f, 0.f, 0.f};
        #pragma unroll
        for (int kd = 0; kd < 2; ++kd)
            #pragma unroll
            for (int ni = 0; ni < 4; ++ni) {
                const bf16x8 kf = *(const bf16x8*)&Ks[(ni * 16 + l15) * 72 + kd * 32 + l4 * 8];
                sf[ni] = __builtin_amdgcn_mfma_f32_16x16x32_bf16(kf, qf[kd], sf[ni], 0, 0, 0);
            }

        // ---- softmax-lite: P = exp2(sf + bias2), no max-sub, per-lane deferred sum
        float p[4][4];
        if (kt == qt) {
            #pragma unroll
            for (int ni = 0; ni < 4; ++ni)
                #pragma unroll
                for (int j = 0; j < 4; ++j) {
                    const float e = (cb[ni][j] > 0.f)
                        ? 0.f
                        : __builtin_amdgcn_exp2f(sf[ni][j] + cb[ni][j]);
                    p[ni][j] = e;
                    lsum += e;
                }
        } else {
            const float dstep = slope2 * (float)((kt << 6) - i0);
            #pragma unroll
            for (int ni = 0; ni < 4; ++ni)
                #pragma unroll
                for (int j = 0; j < 4; ++j) {
                    const float e = __builtin_amdgcn_exp2f(sf[ni][j] + (cb[ni][j] + dstep));
                    p[ni][j] = e;
                    lsum += e;
                }
        }

        // ---- stage P [query][key]: 4x b64 writes (4 contiguous keys each)
        #pragma unroll
        for (int ni = 0; ni < 4; ++ni) {
            bf16x4 pk;
            pk[0] = (__bf16)p[ni][0]; pk[1] = (__bf16)p[ni][1];
            pk[2] = (__bf16)p[ni][2]; pk[3] = (__bf16)p[ni][3];
            *(bf16x4*)&psw[l15 * 72 + ni * 16 + l4 * 4] = pk;
        }
        asm volatile("" ::: "memory");

        // ---- PV: acc[query][d] += P @ V   (A=P[query][key], B=Vt[d][key])
        #pragma unroll
        for (int kk = 0; kk < 2; ++kk) {
            const bf16x8 pa = *(const bf16x8*)&psw[l15 * 72 + kk * 32 + l4 * 8];
            #pragma unroll
            for (int ni = 0; ni < 4; ++ni) {
                const int d = ni * 16 + l15;
                const int pc = ((kk * 4 + l4) ^ (d >> 3)) & 7;
                const bf16x8 bv = *(const bf16x8*)&Vt[d * 72 + pc * 8];
                acc[ni] = __builtin_amdgcn_mfma_f32_16x16x32_bf16(pa, bv, acc[ni], 0, 0, 0);
            }
        }
    }

    // ---- final l reduction: combine the 4 key-partitions of each query, broadcast
    lsum += __shfl_xor(lsum, 16, 64);
    lsum += __shfl_xor(lsum, 32, 64);
    float linv[4];
    #pragma unroll
    for (int j = 0; j < 4; ++j)
        linv[j] = 1.f / __shfl(lsum, l4 * 4 + j, 64);

    // ---- epilogue (acc layout: row=query=l4*4+j, col=d=ni*16+l15)
    #pragma unroll
    for (int ni = 0; ni < 4; ++ni) {
        const int col = h * 64 + ni * 16 + l15;
        #pragma unroll
        for (int j = 0; j < 4; ++j) {
            const int row = i0 + wid * 16 + l4 * 4 + j;
            ctx[(rowb + row) * (size_t)D_ + col] = (__bf16)(acc[ni][j] * linv[j]);
        }
    }
}

// ---------------- launch ----------------------------------------------------------------
extern "C" void kernel_launch(void* const* d_in, const int* in_sizes, int n_in,
                              void* d_out, int out_size, void* d_ws, size_t ws_size,
                              hipStream_t stream) {
    const float* src     = (const float*)d_in[0];
    const float* norm_w  = (const float*)d_in[1];
    const float* norm_b  = (const float*)d_in[2];
    const float* wqkv_w  = (const float*)d_in[3];
    const float* wqkv_b  = (const float*)d_in[4];
    const float* out_w   = (const float*)d_in[5];
    const float* out_b   = (const float*)d_in[6];
    const float* fnorm_w = (const float*)d_in[7];
    const float* fnorm_b = (const float*)d_in[8];
    const float* ff1_w   = (const float*)d_in[9];
    const float* ff1_b   = (const float*)d_in[10];
    const float* ff2_w   = (const float*)d_in[11];
    const float* ff2_b   = (const float*)d_in[12];
    float* out = (float*)d_out;

    const int M = 2 * S_;
    const size_t MB = 1u << 20;
    char* W = (char*)d_ws;
    unsigned short* wqkvT = (unsigned short*)(W);
    unsigned short* outT  = (unsigned short*)(W + 6  * MB);
    unsigned short* ff1T  = (unsigned short*)(W + 8  * MB);
    unsigned short* ff2T  = (unsigned short*)(W + 16 * MB);
    unsigned short* h1    = (unsigned short*)(W + 24 * MB);
    unsigned short* qkv   = (unsigned short*)(W + 32 * MB);
    unsigned short* ctx   = (unsigned short*)(W + 24 * MB);
    unsigned short* h2    = (unsigned short*)(W + 32 * MB);
    unsigned short* ffmid = (unsigned short*)(W + 40 * MB);
    float*          src2  = (float*)        (W + 80 * MB);

    wcast_kernel<<<dim3(3072/64, 1024/64), 256, 0, stream>>>(wqkv_w, wqkvT, 1024, 3072);
    wcast_kernel<<<dim3(1024/64, 1024/64), 256, 0, stream>>>(out_w,  outT,  1024, 1024);
    wcast_kernel<<<dim3(4096/64, 1024/64), 256, 0, stream>>>(ff1_w,  ff1T,  1024, 4096);
    wcast_kernel<<<dim3(1024/64, 4096/64), 256, 0, stream>>>(ff2_w,  ff2T,  4096, 1024);

    // 1) h1 = LN(src) -> bf16
    ln_kernel<true><<<M, 256, 0, stream>>>(src, norm_w, norm_b, h1);
    // 2) qkv = h1 @ wqkv_w + wqkv_b -> bf16  [4096 x 3072]  (768 blocks, BN=128)
    bgemm_kernel<0, true, 128><<<(3072/128) * (M/128), 256, 0, stream>>>(
        (const __bf16*)h1, (const __bf16*)wqkvT, wqkv_b, nullptr, qkv, M, 3072, 1024);
    // 3) ctx = flash-attn(q,k,v) -> bf16  (1024 blocks: 32 qt x 32 bh)
    attn_kernel<<<1024, 256, 0, stream>>>((const __bf16*)qkv, (__bf16*)ctx);
    // 4) src2 = src + ctx @ out_w + out_b  fp32  (512 blocks, BN=64)
    bgemm_kernel<2, false, 64><<<(1024/64) * (M/128), 256, 0, stream>>>(
        (const __bf16*)ctx, (const __bf16*)outT, out_b, src, src2, M, 1024, 1024);
    // 5) h2 = LN(src2) -> bf16
    ln_kernel<true><<<M, 256, 0, stream>>>(src2, fnorm_w, fnorm_b, h2);
    // 6) ffmid = relu(h2 @ ff1_w + ff1_b) -> bf16  [4096 x 4096]  (1024 blocks, BN=128)
    bgemm_kernel<1, true, 128><<<(4096/128) * (M/128), 256, 0, stream>>>(
        (const __bf16*)h2, (const __bf16*)ff1T, ff1_b, nullptr, ffmid, M, 4096, 1024);
    // 7) out = src2 + ffmid @ ff2_w + ff2_b  fp32  (512 blocks, BN=64)
    bgemm_kernel<2, false, 64><<<(1024/64) * (M/128), 256, 0, stream>>>(
        (const __bf16*)ffmid, (const __bf16*)ff2T, ff2_b, src2, out, M, 1024, 4096);
}